// Round 2
// baseline (1650.965 us; speedup 1.0000x reference)
//
#include <hip/hip_runtime.h>
#include <hip/hip_bf16.h>
#include <math.h>

constexpr int B = 8;
constexpr int N = 50000;
constexpr int E = 400000;
constexpr float BN_EPS = 1e-5f;
constexpr float NEG = 0.01f;

// ------------------------- small helpers -------------------------

__device__ __forceinline__ unsigned clamp_src(int s) {
    unsigned u = (unsigned)s;
    return (u < (unsigned)N) ? u : 0u;
}

__device__ __forceinline__ unsigned pack_bf16(float a, float b) {
    unsigned ua = __float_as_uint(a);
    unsigned ub = __float_as_uint(b);
    ua = (ua + 0x7FFFu + ((ua >> 16) & 1u)) >> 16;
    ub = (ub + 0x7FFFu + ((ub >> 16) & 1u)) >> 16;
    return (ub << 16) | (ua & 0xFFFFu);
}
__device__ __forceinline__ float unpack_lo(unsigned u) { return __uint_as_float(u << 16); }
__device__ __forceinline__ float unpack_hi(unsigned u) { return __uint_as_float(u & 0xFFFF0000u); }

template<bool ZBF16>
__device__ __forceinline__ void store_row64(void* op, const float acc[64]) {
    if constexpr (!ZBF16) {
        float* p = (float*)op;
#pragma unroll
        for (int q = 0; q < 16; ++q)
            *(float4*)(p + q * 4) = make_float4(acc[q * 4], acc[q * 4 + 1], acc[q * 4 + 2], acc[q * 4 + 3]);
    } else {
        uint4* p = (uint4*)op;
#pragma unroll
        for (int q = 0; q < 8; ++q) {
            uint4 v;
            v.x = pack_bf16(acc[q * 8 + 0], acc[q * 8 + 1]);
            v.y = pack_bf16(acc[q * 8 + 2], acc[q * 8 + 3]);
            v.z = pack_bf16(acc[q * 8 + 4], acc[q * 8 + 5]);
            v.w = pack_bf16(acc[q * 8 + 6], acc[q * 8 + 7]);
            p[q] = v;
        }
    }
}

template<bool ZBF16>
__device__ __forceinline__ void load_row64(const void* ip, float acc[64]) {
    if constexpr (!ZBF16) {
        const float* p = (const float*)ip;
#pragma unroll
        for (int q = 0; q < 16; ++q) {
            float4 v = *(const float4*)(p + q * 4);
            acc[q * 4 + 0] = v.x; acc[q * 4 + 1] = v.y; acc[q * 4 + 2] = v.z; acc[q * 4 + 3] = v.w;
        }
    } else {
        const uint4* p = (const uint4*)ip;
#pragma unroll
        for (int q = 0; q < 8; ++q) {
            uint4 v = p[q];
            acc[q * 8 + 0] = unpack_lo(v.x); acc[q * 8 + 1] = unpack_hi(v.x);
            acc[q * 8 + 2] = unpack_lo(v.y); acc[q * 8 + 3] = unpack_hi(v.y);
            acc[q * 8 + 4] = unpack_lo(v.z); acc[q * 8 + 5] = unpack_hi(v.z);
            acc[q * 8 + 6] = unpack_lo(v.w); acc[q * 8 + 7] = unpack_hi(v.w);
        }
    }
}

// ------------------------- CSR construction -------------------------

__global__ __launch_bounds__(256) void deg_kernel(const int* __restrict__ col, float* __restrict__ deg) {
    int e = blockIdx.x * blockDim.x + threadIdx.x;
    if (e < E) atomicAdd(&deg[clamp_src(col[e])], 1.0f);
}

__global__ __launch_bounds__(256) void scan1_kernel(const float* __restrict__ deg,
                                                    int* __restrict__ part, int* __restrict__ bsum) {
    __shared__ int sm[4];
    int i = blockIdx.x * blockDim.x + threadIdx.x;
    int v = (i < N) ? (int)deg[i] : 0;
    int lane = threadIdx.x & 63, wv = threadIdx.x >> 6;
    int x = v;
#pragma unroll
    for (int off = 1; off < 64; off <<= 1) {
        int t = __shfl_up(x, off);
        if (lane >= off) x += t;
    }
    if (lane == 63) sm[wv] = x;
    __syncthreads();
    int add = 0;
#pragma unroll
    for (int w = 0; w < 4; ++w) if (w < wv) add += sm[w];
    if (i < N) part[i] = x - v + add;
    if (threadIdx.x == blockDim.x - 1) bsum[blockIdx.x] = x + add;
}

__global__ __launch_bounds__(256) void scan2_kernel(const int* __restrict__ bsum, int* __restrict__ boff,
                                                    int nb, int* __restrict__ rowptr) {
    __shared__ int sm[4];
    int i = threadIdx.x;
    int v = (i < nb) ? bsum[i] : 0;
    int lane = i & 63, wv = i >> 6;
    int x = v;
#pragma unroll
    for (int off = 1; off < 64; off <<= 1) {
        int t = __shfl_up(x, off);
        if (lane >= off) x += t;
    }
    if (lane == 63) sm[wv] = x;
    __syncthreads();
    int add = 0;
#pragma unroll
    for (int w = 0; w < 4; ++w) if (w < wv) add += sm[w];
    if (i < nb) boff[i] = x - v + add;
    if (i == 0) rowptr[N] = E;
}

__global__ __launch_bounds__(256) void scan3_kernel(const int* __restrict__ part, const int* __restrict__ boff,
                                                    int* __restrict__ rowptr) {
    int i = blockIdx.x * blockDim.x + threadIdx.x;
    if (i < N) rowptr[i] = part[i] + boff[blockIdx.x];
}

__global__ __launch_bounds__(256) void fill_kernel(const int* __restrict__ row, const int* __restrict__ col,
                                                   const float* __restrict__ deg, const int* __restrict__ rowptr,
                                                   int* __restrict__ cursor, int* __restrict__ csr_src,
                                                   float* __restrict__ csr_w) {
    int e = blockIdx.x * blockDim.x + threadIdx.x;
    if (e >= E) return;
    unsigned r = clamp_src(row[e]), c = clamp_src(col[e]);
    float dr = deg[r], dc = deg[c];
    float w = (dr > 0.f ? rsqrtf(dr) : 0.f) * (dc > 0.f ? rsqrtf(dc) : 0.f);
    unsigned p = (unsigned)(rowptr[c] + atomicAdd(&cursor[c], 1));
    if (p >= (unsigned)E) p = E - 1;   // defensive: never fault
    csr_src[p] = (int)r;
    csr_w[p] = w;
}

// ------------------------- 4-dim propagation (layer 0) -------------------------
// 1-D grid, b = blockIdx.x & 7 -> batch pinned to XCD (round-robin dispatch)

__global__ __launch_bounds__(256) void xprop_kernel(const float* __restrict__ xin, const int* __restrict__ rowptr,
                                                    const int* __restrict__ csr_src, const float* __restrict__ csr_w,
                                                    float* __restrict__ xout) {
    int b = blockIdx.x & 7;
    int nb = blockIdx.x >> 3;
    int n = nb * blockDim.x + threadIdx.x;
    if (n >= N) return;
    float4 acc = make_float4(0.f, 0.f, 0.f, 0.f);
    int beg = rowptr[n], end = rowptr[n + 1];
    if (beg < 0) beg = 0;
    if (end > E) end = E;
    const float* base = xin + (size_t)b * N * 4;
    for (int i = beg; i < end; ++i) {
        unsigned s = clamp_src(csr_src[i]);
        float w = csr_w[i];
        float4 v = *(const float4*)(base + (size_t)s * 4);
        acc.x = fmaf(w, v.x, acc.x);
        acc.y = fmaf(w, v.y, acc.y);
        acc.z = fmaf(w, v.z, acc.z);
        acc.w = fmaf(w, v.w, acc.w);
    }
    *(float4*)(xout + ((size_t)b * N + n) * 4) = acc;
}

// ------------------------- layer 0 fused: 16->64 matmul + BN + leaky -------------------------
// lane mapping: 8 nodes x 8 batches per wave; BN over batch via shfl_xor(1,2,4).
// Computes all 8 batches (BN needs them), writes only batches [b0, b0+cc).

__global__ __launch_bounds__(256) void fused0_kernel(const float* __restrict__ x0, const float* __restrict__ x1,
                                                     const float* __restrict__ x2, const float* __restrict__ x3,
                                                     const float* __restrict__ W0, const float* __restrict__ bias,
                                                     const float* __restrict__ gamma, const float* __restrict__ beta,
                                                     int b0, int cc, float* __restrict__ h1c) {
    int gid = blockIdx.x * blockDim.x + threadIdx.x;
    int wave = gid >> 6, lane = gid & 63;
    int n = wave * 8 + (lane >> 3);
    int b = lane & 7;
    if (n >= N) return;
    size_t ro = ((size_t)b * N + n) * 4;
    float xv[16];
    *(float4*)(xv + 0)  = *(const float4*)(x0 + ro);
    *(float4*)(xv + 4)  = *(const float4*)(x1 + ro);
    *(float4*)(xv + 8)  = *(const float4*)(x2 + ro);
    *(float4*)(xv + 12) = *(const float4*)(x3 + ro);
    float acc[64];
#pragma unroll
    for (int f = 0; f < 64; ++f) acc[f] = bias[f];
#pragma unroll
    for (int kf = 0; kf < 16; ++kf) {
        float xs = xv[kf];
#pragma unroll
        for (int f = 0; f < 64; ++f)
            acc[f] = fmaf(xs, W0[kf * 64 + f], acc[f]);
    }
    const float* gp = gamma + (size_t)n * 64;
    const float* bp = beta + (size_t)n * 64;
#pragma unroll
    for (int f = 0; f < 64; ++f) {
        float v = acc[f];
        float s = v, s2 = v * v;
        s += __shfl_xor(s, 1);  s += __shfl_xor(s, 2);  s += __shfl_xor(s, 4);
        s2 += __shfl_xor(s2, 1); s2 += __shfl_xor(s2, 2); s2 += __shfl_xor(s2, 4);
        float mean = s * 0.125f;
        float var = fmaf(-mean, mean, s2 * 0.125f);
        float xn = (v - mean) * rsqrtf(var + BN_EPS);
        float o = fmaf(gp[f], xn, bp[f]);
        acc[f] = (o >= 0.f) ? o : NEG * o;
    }
    if (b >= b0 && b < b0 + cc) {
        float* hp = h1c + ((size_t)(b - b0) * N + n) * 64;
        store_row64<false>(hp, acc);
    }
}

// ------------------------- dense 64x64 + gather pieces -------------------------

__device__ __forceinline__ void dense64(const float* __restrict__ hp, const float* __restrict__ W, float acc[64]) {
#pragma unroll 1
    for (int kk = 0; kk < 4; ++kk) {
        float hreg[16];
#pragma unroll
        for (int q = 0; q < 4; ++q)
            *(float4*)(hreg + q * 4) = *(const float4*)(hp + kk * 16 + q * 4);
        const float* Wp = W + kk * 16 * 64;
#pragma unroll
        for (int k = 0; k < 16; ++k) {
            float hv = hreg[k];
#pragma unroll
            for (int c = 0; c < 64; ++c)
                acc[c] = fmaf(hv, Wp[k * 64 + c], acc[c]);
        }
    }
}

__device__ __forceinline__ void gather64(const float* __restrict__ ub, int beg, int end,
                                         const int* __restrict__ csr_src, const float* __restrict__ csr_w,
                                         float acc[64]) {
    if (beg < 0) beg = 0;
    if (end > E) end = E;
    for (int i = beg; i < end; ++i) {
        unsigned s = clamp_src(csr_src[i]);
        float w = csr_w[i];
        const float4* up = (const float4*)(ub + (size_t)s * 64);
#pragma unroll
        for (int q = 0; q < 16; ++q) {
            float4 v = up[q];
            acc[q * 4 + 0] = fmaf(w, v.x, acc[q * 4 + 0]);
            acc[q * 4 + 1] = fmaf(w, v.y, acc[q * 4 + 1]);
            acc[q * 4 + 2] = fmaf(w, v.z, acc[q * 4 + 2]);
            acc[q * 4 + 3] = fmaf(w, v.w, acc[q * 4 + 3]);
        }
    }
}

// u_out[bl] = h[bl] @ W   (start of Horner)
__global__ __launch_bounds__(256) void mm64_kernel(const float* __restrict__ h, const float* __restrict__ W,
                                                   float* __restrict__ out, int bshift, int bmask) {
    int bl = blockIdx.x & bmask;
    int nb = blockIdx.x >> bshift;
    int n = nb * blockDim.x + threadIdx.x;
    if (n >= N) return;
    float acc[64];
#pragma unroll
    for (int f = 0; f < 64; ++f) acc[f] = 0.f;
    dense64(h + ((size_t)bl * N + n) * 64, W, acc);
    store_row64<false>(out + ((size_t)bl * N + n) * 64, acc);
}

// out[bl] = A u_in[bl] + h[bl] @ W (+ bias); ZBF16 selects z storage type
template<bool ZBF16>
__global__ __launch_bounds__(256) void hop64_kernel(const float* __restrict__ u_in, const int* __restrict__ rowptr,
                                                    const int* __restrict__ csr_src, const float* __restrict__ csr_w,
                                                    const float* __restrict__ h, const float* __restrict__ W,
                                                    const float* __restrict__ bias,
                                                    void* __restrict__ out, int bshift, int bmask) {
    int bl = blockIdx.x & bmask;
    int nb = blockIdx.x >> bshift;
    int n = nb * blockDim.x + threadIdx.x;
    if (n >= N) return;
    float acc[64];
    if (bias) {
#pragma unroll
        for (int f = 0; f < 64; ++f) acc[f] = bias[f];
    } else {
#pragma unroll
        for (int f = 0; f < 64; ++f) acc[f] = 0.f;
    }
    gather64(u_in + (size_t)bl * N * 64, rowptr[n], rowptr[n + 1], csr_src, csr_w, acc);
    dense64(h + ((size_t)bl * N + n) * 64, W, acc);
    char* op = (char*)out + ((size_t)bl * N + n) * 64 * (ZBF16 ? 2 : 4);
    store_row64<ZBF16>(op, acc);
}

// fused final hop (full-batch path): gather + dense + bias + BN + leaky + project
__global__ __launch_bounds__(256) void hop64_final_kernel(const float* __restrict__ u_in, const int* __restrict__ rowptr,
                                                          const int* __restrict__ csr_src, const float* __restrict__ csr_w,
                                                          const float* __restrict__ h, const float* __restrict__ W,
                                                          const float* __restrict__ bias,
                                                          const float* __restrict__ gamma, const float* __restrict__ beta,
                                                          const float* __restrict__ W2, float* __restrict__ y) {
    int gid = blockIdx.x * blockDim.x + threadIdx.x;
    int wave = gid >> 6, lane = gid & 63;
    int n = wave * 8 + (lane >> 3);
    int b = lane & 7;
    if (n >= N) return;
    float acc[64];
#pragma unroll
    for (int f = 0; f < 64; ++f) acc[f] = bias[f];
    gather64(u_in + (size_t)b * N * 64, rowptr[n], rowptr[n + 1], csr_src, csr_w, acc);
    dense64(h + ((size_t)b * N + n) * 64, W, acc);
    const float* gp = gamma + (size_t)n * 64;
    const float* bp = beta + (size_t)n * 64;
#pragma unroll
    for (int f = 0; f < 64; ++f) {
        float v = acc[f];
        float s = v, s2 = v * v;
        s += __shfl_xor(s, 1);  s += __shfl_xor(s, 2);  s += __shfl_xor(s, 4);
        s2 += __shfl_xor(s2, 1); s2 += __shfl_xor(s2, 2); s2 += __shfl_xor(s2, 4);
        float mean = s * 0.125f;
        float var = fmaf(-mean, mean, s2 * 0.125f);
        float xn = (v - mean) * rsqrtf(var + BN_EPS);
        float o = fmaf(gp[f], xn, bp[f]);
        acc[f] = (o >= 0.f) ? o : NEG * o;
    }
    size_t bn3 = ((size_t)b * N + n) * 3;
#pragma unroll
    for (int k = 0; k < 4; ++k) {
#pragma unroll
        for (int c = 0; c < 3; ++c) {
            float s = 0.f;
#pragma unroll
            for (int f = 0; f < 64; ++f)
                s = fmaf(acc[f], W2[k * 192 + f * 3 + c], s);
            y[(size_t)k * B * N * 3 + bn3 + c] = s;
        }
    }
}

// chunked path: BN + leaky + project from stored pre-BN z (full batch)
template<bool ZBF16>
__global__ __launch_bounds__(256) void bn_project_kernel(const void* __restrict__ z,
                                                         const float* __restrict__ gamma, const float* __restrict__ beta,
                                                         const float* __restrict__ W2, float* __restrict__ y) {
    int gid = blockIdx.x * blockDim.x + threadIdx.x;
    int wave = gid >> 6, lane = gid & 63;
    int n = wave * 8 + (lane >> 3);
    int b = lane & 7;
    if (n >= N) return;
    float acc[64];
    const char* zp = (const char*)z + ((size_t)b * N + n) * 64 * (ZBF16 ? 2 : 4);
    load_row64<ZBF16>(zp, acc);
    const float* gp = gamma + (size_t)n * 64;
    const float* bp = beta + (size_t)n * 64;
#pragma unroll
    for (int f = 0; f < 64; ++f) {
        float v = acc[f];
        float s = v, s2 = v * v;
        s += __shfl_xor(s, 1);  s += __shfl_xor(s, 2);  s += __shfl_xor(s, 4);
        s2 += __shfl_xor(s2, 1); s2 += __shfl_xor(s2, 2); s2 += __shfl_xor(s2, 4);
        float mean = s * 0.125f;
        float var = fmaf(-mean, mean, s2 * 0.125f);
        float xn = (v - mean) * rsqrtf(var + BN_EPS);
        float o = fmaf(gp[f], xn, bp[f]);
        acc[f] = (o >= 0.f) ? o : NEG * o;
    }
    size_t bn3 = ((size_t)b * N + n) * 3;
#pragma unroll
    for (int k = 0; k < 4; ++k) {
#pragma unroll
        for (int c = 0; c < 3; ++c) {
            float s = 0.f;
#pragma unroll
            for (int f = 0; f < 64; ++f)
                s = fmaf(acc[f], W2[k * 192 + f * 3 + c], s);
            y[(size_t)k * B * N * 3 + bn3 + c] = s;
        }
    }
}

// ------------------------- 3-dim propagation (layer 2 Horner) -------------------------

__global__ __launch_bounds__(256) void qprop_kernel(const float* __restrict__ vin, const int* __restrict__ rowptr,
                                                    const int* __restrict__ csr_src, const float* __restrict__ csr_w,
                                                    const float* __restrict__ add, float* __restrict__ vout) {
    int b = blockIdx.x & 7;
    int nb = blockIdx.x >> 3;
    int n = nb * blockDim.x + threadIdx.x;
    if (n >= N) return;
    float a0 = 0.f, a1 = 0.f, a2 = 0.f;
    int beg = rowptr[n], end = rowptr[n + 1];
    if (beg < 0) beg = 0;
    if (end > E) end = E;
    const float* base = vin + (size_t)b * N * 3;
    for (int i = beg; i < end; ++i) {
        unsigned s = clamp_src(csr_src[i]);
        float w = csr_w[i];
        const float* p = base + (size_t)s * 3;
        a0 = fmaf(w, p[0], a0);
        a1 = fmaf(w, p[1], a1);
        a2 = fmaf(w, p[2], a2);
    }
    const float* ap = add + ((size_t)b * N + n) * 3;
    float* op = vout + ((size_t)b * N + n) * 3;
    op[0] = a0 + ap[0];
    op[1] = a1 + ap[1];
    op[2] = a2 + ap[2];
}

__global__ __launch_bounds__(256) void qfinal_kernel(const float* __restrict__ vin, const int* __restrict__ rowptr,
                                                     const int* __restrict__ csr_src, const float* __restrict__ csr_w,
                                                     const float* __restrict__ y0, const float* __restrict__ b2,
                                                     const float* __restrict__ vmin, const float* __restrict__ vmax,
                                                     float* __restrict__ out) {
    int b = blockIdx.x & 7;
    int nb = blockIdx.x >> 3;
    int n = nb * blockDim.x + threadIdx.x;
    if (n >= N) return;
    float a0 = 0.f, a1 = 0.f, a2 = 0.f;
    int beg = rowptr[n], end = rowptr[n + 1];
    if (beg < 0) beg = 0;
    if (end > E) end = E;
    const float* base = vin + (size_t)b * N * 3;
    for (int i = beg; i < end; ++i) {
        unsigned s = clamp_src(csr_src[i]);
        float w = csr_w[i];
        const float* p = base + (size_t)s * 3;
        a0 = fmaf(w, p[0], a0);
        a1 = fmaf(w, p[1], a1);
        a2 = fmaf(w, p[2], a2);
    }
    size_t bn3 = ((size_t)b * N + n) * 3;
    const float* yp = y0 + bn3;
    float g0 = a0 + yp[0] + b2[0];
    float g1 = a1 + yp[1] + b2[1];
    float g2 = a2 + yp[2] + b2[2];
    float mn0 = vmin[n * 3 + 0], mx0 = vmax[n * 3 + 0];
    float mn1 = vmin[n * 3 + 1], mx1 = vmax[n * 3 + 1];
    float mn2 = vmin[n * 3 + 2], mx2 = vmax[n * 3 + 2];
    float* op = out + bn3;
    op[0] = mn0 + (mx0 - mn0) / (1.f + expf(g0));
    op[1] = mn1 + (mx1 - mn1) / (1.f + expf(g1));
    op[2] = mn2 + (mx2 - mn2) / (1.f + expf(g2));
}

// ------------------------- host launcher -------------------------

extern "C" void kernel_launch(void* const* d_in, const int* in_sizes, int n_in,
                              void* d_out, int out_size, void* d_ws, size_t ws_size,
                              hipStream_t stream) {
    const float* x      = (const float*)d_in[0];
    const int*   ei     = (const int*)d_in[1];
    const int*   rowi   = ei;
    const int*   coli   = ei + E;
    const float* vmin   = (const float*)d_in[2];
    const float* vmax   = (const float*)d_in[3];
    const float* W0     = (const float*)d_in[4];
    const float* b0v    = (const float*)d_in[5];
    const float* W1     = (const float*)d_in[6];
    const float* b1v    = (const float*)d_in[7];
    const float* W2     = (const float*)d_in[8];
    const float* b2v    = (const float*)d_in[9];
    const float* gamma0 = (const float*)d_in[10];
    const float* beta0  = (const float*)d_in[11];
    const float* gamma1 = (const float*)d_in[12];
    const float* beta1  = (const float*)d_in[13];
    float* out = (float*)d_out;

    // ---- workspace accounting (floats) ----
    const size_t PC   = (size_t)N * 64;        // 3.2M floats per batch of 64-dim state
    const size_t BN4  = (size_t)B * N * 4;
    const size_t BN3  = (size_t)B * N * 3;
    auto rnd = [](size_t nf) { return (nf + 63) & ~(size_t)63; };
    size_t common_fl = rnd(N) * 3 /*deg,part,cursor*/ + rnd(N + 1) /*rowptr*/ + 256 * 2
                     + rnd(E) * 2 /*csr_w,csr_src*/
                     + rnd((size_t)B * N * 4 / 4) * 0; // (placeholder, computed below)
    // recompute exactly in allocation order to avoid drift:
    common_fl = 0;
    {
        size_t o = 0;
        auto a = [&](size_t nf) { o += rnd(nf); };
        a(N); a(E); a(N + 1); a(N); a(256); a(256); a(N); a(E);   // deg,csr_w,rowptr,part,bsum,boff,cursor,csr_src
        a(BN4); a(BN4); a(BN4);                                    // x1,x2,x3
        a(4 * BN3);                                                // y
        a(BN3); a(BN3);                                            // v_a, v_b
        common_fl = o;
    }
    const size_t avail_fl = ws_size / 4;
    // mode selection
    bool fused = false, zb16 = false;
    int cc = 1;
    if (avail_fl >= common_fl + 24 * PC) { fused = true; cc = 8; }
    else if (avail_fl >= common_fl + 8 * PC + 12 * PC) { cc = 4; }   // z(8PC) + 3*4PC
    else if (avail_fl >= common_fl + 8 * PC + 6 * PC)  { cc = 2; }
    else if (avail_fl >= common_fl + 8 * PC + 3 * PC)  { cc = 1; }
    else { zb16 = true; cc = 1; }                                    // z as bf16 (4PC) + 3PC

    // ---- allocate ----
    size_t off = 0;
    auto alloc = [&](size_t nfloats) -> float* {
        float* p = (float*)d_ws + off;
        off += (nfloats + 63) & ~(size_t)63;
        return p;
    };
    float* deg     = alloc(N);
    float* csr_w   = alloc(E);
    int*   rowptr  = (int*)alloc(N + 1);
    int*   part    = (int*)alloc(N);
    int*   bsum    = (int*)alloc(256);
    int*   boff    = (int*)alloc(256);
    int*   cursor  = (int*)alloc(N);
    int*   csr_src = (int*)alloc(E);
    float* x1 = alloc(BN4);
    float* x2 = alloc(BN4);
    float* x3 = alloc(BN4);
    float* y  = alloc(4 * BN3);
    float* v_a = alloc(BN3);
    float* v_b = alloc(BN3);
    float* h1c = alloc((size_t)cc * PC);
    float* u_a = alloc((size_t)cc * PC);
    float* u_b = alloc((size_t)cc * PC);
    void*  z   = nullptr;
    if (!fused) z = zb16 ? (void*)alloc(4 * PC) : (void*)alloc(8 * PC);

    const int GE = (E + 255) / 256;
    const int GN = (N + 255) / 256;
    const int GT = (B * N + 255) / 256;
    dim3 blk(256);
    int bshift = (cc == 8) ? 3 : (cc == 4) ? 2 : (cc == 2) ? 1 : 0;
    int bmask = cc - 1;

    // CSR build
    hipMemsetAsync(deg, 0, N * sizeof(float), stream);
    hipMemsetAsync(cursor, 0, N * sizeof(int), stream);
    deg_kernel<<<GE, blk, 0, stream>>>(coli, deg);
    scan1_kernel<<<GN, blk, 0, stream>>>(deg, part, bsum);
    scan2_kernel<<<1, blk, 0, stream>>>(bsum, boff, GN, rowptr);
    scan3_kernel<<<GN, blk, 0, stream>>>(part, boff, rowptr);
    fill_kernel<<<GE, blk, 0, stream>>>(rowi, coli, deg, rowptr, cursor, csr_src, csr_w);

    // layer 0 propagation at 4-dim (full batch, batch->XCD pinned)
    xprop_kernel<<<GN * 8, blk, 0, stream>>>(x,  rowptr, csr_src, csr_w, x1);
    xprop_kernel<<<GN * 8, blk, 0, stream>>>(x1, rowptr, csr_src, csr_w, x2);
    xprop_kernel<<<GN * 8, blk, 0, stream>>>(x2, rowptr, csr_src, csr_w, x3);

    // layer 1 (Horner over W1), chunked over batches
    for (int b0 = 0; b0 < B; b0 += cc) {
        fused0_kernel<<<GT, blk, 0, stream>>>(x, x1, x2, x3, W0, b0v, gamma0, beta0, b0, cc, h1c);
        mm64_kernel<<<GN * cc, blk, 0, stream>>>(h1c, W1 + 3 * 4096, u_a, bshift, bmask);
        hop64_kernel<false><<<GN * cc, blk, 0, stream>>>(u_a, rowptr, csr_src, csr_w, h1c, W1 + 2 * 4096,
                                                         nullptr, u_b, bshift, bmask);
        hop64_kernel<false><<<GN * cc, blk, 0, stream>>>(u_b, rowptr, csr_src, csr_w, h1c, W1 + 1 * 4096,
                                                         nullptr, u_a, bshift, bmask);
        if (fused) {
            hop64_final_kernel<<<GT, blk, 0, stream>>>(u_a, rowptr, csr_src, csr_w, h1c, W1, b1v,
                                                       gamma1, beta1, W2, y);
        } else if (zb16) {
            void* zo = (char*)z + (size_t)b0 * N * 64 * 2;
            hop64_kernel<true><<<GN * cc, blk, 0, stream>>>(u_a, rowptr, csr_src, csr_w, h1c, W1,
                                                            b1v, zo, bshift, bmask);
        } else {
            void* zo = (char*)z + (size_t)b0 * N * 64 * 4;
            hop64_kernel<false><<<GN * cc, blk, 0, stream>>>(u_a, rowptr, csr_src, csr_w, h1c, W1,
                                                             b1v, zo, bshift, bmask);
        }
    }
    if (!fused) {
        if (zb16) bn_project_kernel<true><<<GT, blk, 0, stream>>>(z, gamma1, beta1, W2, y);
        else      bn_project_kernel<false><<<GT, blk, 0, stream>>>(z, gamma1, beta1, W2, y);
    }

    // layer 2 Horner at 3-dim
    qprop_kernel<<<GN * 8, blk, 0, stream>>>(y + 3 * BN3, rowptr, csr_src, csr_w, y + 2 * BN3, v_a);
    qprop_kernel<<<GN * 8, blk, 0, stream>>>(v_a, rowptr, csr_src, csr_w, y + 1 * BN3, v_b);
    qfinal_kernel<<<GN * 8, blk, 0, stream>>>(v_b, rowptr, csr_src, csr_w, y, b2v, vmin, vmax, out);
}

// Round 3
// 1105.067 us; speedup vs baseline: 1.4940x; 1.4940x over previous
//
#include <hip/hip_runtime.h>
#include <math.h>

constexpr int B = 8;
constexpr int N = 50000;
constexpr int E = 400000;
constexpr float BN_EPS = 1e-5f;
constexpr float NEG = 0.01f;

// ------------------------- bf16 pack/unpack helpers -------------------------

__device__ __forceinline__ unsigned clamp_src(int s) {
    unsigned u = (unsigned)s;
    return (u < (unsigned)N) ? u : 0u;
}

__device__ __forceinline__ unsigned pack_bf16(float a, float b) {
    unsigned ua = __float_as_uint(a);
    unsigned ub = __float_as_uint(b);
    ua = (ua + 0x7FFFu + ((ua >> 16) & 1u)) >> 16;
    ub = (ub + 0x7FFFu + ((ub >> 16) & 1u)) >> 16;
    return (ub << 16) | (ua & 0xFFFFu);
}
__device__ __forceinline__ float unpack_lo(unsigned u) { return __uint_as_float(u << 16); }
__device__ __forceinline__ float unpack_hi(unsigned u) { return __uint_as_float(u & 0xFFFF0000u); }

// row of 64 floats <-> 128B bf16 (8 x uint4) or 256B fp32
__device__ __forceinline__ void store_row64_f32(float* p, const float acc[64]) {
#pragma unroll
    for (int q = 0; q < 16; ++q)
        *(float4*)(p + q * 4) = make_float4(acc[q * 4], acc[q * 4 + 1], acc[q * 4 + 2], acc[q * 4 + 3]);
}
__device__ __forceinline__ void store_row64_bf(void* op, const float acc[64]) {
    uint4* p = (uint4*)op;
#pragma unroll
    for (int q = 0; q < 8; ++q) {
        uint4 v;
        v.x = pack_bf16(acc[q * 8 + 0], acc[q * 8 + 1]);
        v.y = pack_bf16(acc[q * 8 + 2], acc[q * 8 + 3]);
        v.z = pack_bf16(acc[q * 8 + 4], acc[q * 8 + 5]);
        v.w = pack_bf16(acc[q * 8 + 6], acc[q * 8 + 7]);
        p[q] = v;
    }
}

// ------------------------- CSR construction -------------------------

__global__ __launch_bounds__(256) void deg_kernel(const int* __restrict__ col, float* __restrict__ deg) {
    int e = blockIdx.x * blockDim.x + threadIdx.x;
    if (e < E) atomicAdd(&deg[clamp_src(col[e])], 1.0f);
}

__global__ __launch_bounds__(256) void scan1_kernel(const float* __restrict__ deg,
                                                    int* __restrict__ part, int* __restrict__ bsum) {
    __shared__ int sm[4];
    int i = blockIdx.x * blockDim.x + threadIdx.x;
    int v = (i < N) ? (int)deg[i] : 0;
    int lane = threadIdx.x & 63, wv = threadIdx.x >> 6;
    int x = v;
#pragma unroll
    for (int off = 1; off < 64; off <<= 1) {
        int t = __shfl_up(x, off);
        if (lane >= off) x += t;
    }
    if (lane == 63) sm[wv] = x;
    __syncthreads();
    int add = 0;
#pragma unroll
    for (int w = 0; w < 4; ++w) if (w < wv) add += sm[w];
    if (i < N) part[i] = x - v + add;
    if (threadIdx.x == blockDim.x - 1) bsum[blockIdx.x] = x + add;
}

__global__ __launch_bounds__(256) void scan2_kernel(const int* __restrict__ bsum, int* __restrict__ boff,
                                                    int nb, int* __restrict__ rowptr) {
    __shared__ int sm[4];
    int i = threadIdx.x;
    int v = (i < nb) ? bsum[i] : 0;
    int lane = i & 63, wv = i >> 6;
    int x = v;
#pragma unroll
    for (int off = 1; off < 64; off <<= 1) {
        int t = __shfl_up(x, off);
        if (lane >= off) x += t;
    }
    if (lane == 63) sm[wv] = x;
    __syncthreads();
    int add = 0;
#pragma unroll
    for (int w = 0; w < 4; ++w) if (w < wv) add += sm[w];
    if (i < nb) boff[i] = x - v + add;
    if (i == 0) rowptr[N] = E;
}

__global__ __launch_bounds__(256) void scan3_kernel(const int* __restrict__ part, const int* __restrict__ boff,
                                                    int* __restrict__ rowptr) {
    int i = blockIdx.x * blockDim.x + threadIdx.x;
    if (i < N) rowptr[i] = part[i] + boff[blockIdx.x];
}

__global__ __launch_bounds__(256) void fill_kernel(const int* __restrict__ row, const int* __restrict__ col,
                                                   const float* __restrict__ deg, const int* __restrict__ rowptr,
                                                   int* __restrict__ cursor, int* __restrict__ csr_src,
                                                   float* __restrict__ csr_w) {
    int e = blockIdx.x * blockDim.x + threadIdx.x;
    if (e >= E) return;
    unsigned r = clamp_src(row[e]), c = clamp_src(col[e]);
    float dr = deg[r], dc = deg[c];
    float w = (dr > 0.f ? rsqrtf(dr) : 0.f) * (dc > 0.f ? rsqrtf(dc) : 0.f);
    unsigned p = (unsigned)(rowptr[c] + atomicAdd(&cursor[c], 1));
    if (p >= (unsigned)E) p = E - 1;
    csr_src[p] = (int)r;
    csr_w[p] = w;
}

// ------------------------- 4-dim propagation (layer 0), bf16 out -------------------------

template<bool INBF>
__global__ __launch_bounds__(256) void xprop_kernel(const void* __restrict__ xin, const int* __restrict__ rowptr,
                                                    const int* __restrict__ csr_src, const float* __restrict__ csr_w,
                                                    uint2* __restrict__ xout) {
    int b = blockIdx.x & 7;
    int nb = blockIdx.x >> 3;
    int n = nb * blockDim.x + threadIdx.x;
    if (n >= N) return;
    float a0 = 0.f, a1 = 0.f, a2 = 0.f, a3 = 0.f;
    int beg = rowptr[n], end = rowptr[n + 1];
    if (beg < 0) beg = 0;
    if (end > E) end = E;
    for (int i = beg; i < end; ++i) {
        unsigned s = clamp_src(csr_src[i]);
        float w = csr_w[i];
        if constexpr (!INBF) {
            float4 v = *((const float4*)xin + (size_t)b * N + s);
            a0 = fmaf(w, v.x, a0); a1 = fmaf(w, v.y, a1);
            a2 = fmaf(w, v.z, a2); a3 = fmaf(w, v.w, a3);
        } else {
            uint2 v = *((const uint2*)xin + (size_t)b * N + s);
            a0 = fmaf(w, unpack_lo(v.x), a0); a1 = fmaf(w, unpack_hi(v.x), a1);
            a2 = fmaf(w, unpack_lo(v.y), a2); a3 = fmaf(w, unpack_hi(v.y), a3);
        }
    }
    uint2 o;
    o.x = pack_bf16(a0, a1);
    o.y = pack_bf16(a2, a3);
    xout[(size_t)b * N + n] = o;
}

// ------------------------- layer 0 fused: 16->64 matmul + BN + leaky, full-batch bf16 out ----

__global__ __launch_bounds__(256) void fused0_kernel(const float* __restrict__ x0, const uint2* __restrict__ x1,
                                                     const uint2* __restrict__ x2, const uint2* __restrict__ x3,
                                                     const float* __restrict__ W0, const float* __restrict__ bias,
                                                     const float* __restrict__ gamma, const float* __restrict__ beta,
                                                     void* __restrict__ h1) {
    int gid = blockIdx.x * blockDim.x + threadIdx.x;
    int wave = gid >> 6, lane = gid & 63;
    int n = wave * 8 + (lane >> 3);
    int b = lane & 7;
    if (n >= N) return;
    size_t ro = (size_t)b * N + n;
    float xv[16];
    {
        float4 v = *((const float4*)x0 + ro);
        xv[0] = v.x; xv[1] = v.y; xv[2] = v.z; xv[3] = v.w;
        uint2 u1 = x1[ro], u2 = x2[ro], u3 = x3[ro];
        xv[4] = unpack_lo(u1.x); xv[5] = unpack_hi(u1.x); xv[6] = unpack_lo(u1.y); xv[7] = unpack_hi(u1.y);
        xv[8] = unpack_lo(u2.x); xv[9] = unpack_hi(u2.x); xv[10] = unpack_lo(u2.y); xv[11] = unpack_hi(u2.y);
        xv[12] = unpack_lo(u3.x); xv[13] = unpack_hi(u3.x); xv[14] = unpack_lo(u3.y); xv[15] = unpack_hi(u3.y);
    }
    float acc[64];
#pragma unroll
    for (int f = 0; f < 64; ++f) acc[f] = bias[f];
#pragma unroll
    for (int kf = 0; kf < 16; ++kf) {
        float xs = xv[kf];
#pragma unroll
        for (int f = 0; f < 64; ++f)
            acc[f] = fmaf(xs, W0[kf * 64 + f], acc[f]);
    }
    const float* gp = gamma + (size_t)n * 64;
    const float* bp = beta + (size_t)n * 64;
#pragma unroll
    for (int f = 0; f < 64; ++f) {
        float v = acc[f];
        float s = v, s2 = v * v;
        s += __shfl_xor(s, 1);  s += __shfl_xor(s, 2);  s += __shfl_xor(s, 4);
        s2 += __shfl_xor(s2, 1); s2 += __shfl_xor(s2, 2); s2 += __shfl_xor(s2, 4);
        float mean = s * 0.125f;
        float var = fmaf(-mean, mean, s2 * 0.125f);
        float xn = (v - mean) * rsqrtf(var + BN_EPS);
        float o = fmaf(gp[f], xn, bp[f]);
        acc[f] = (o >= 0.f) ? o : NEG * o;
    }
    store_row64_bf((char*)h1 + ro * 128, acc);
}

// ------------------------- dense 64x64 (bf16 h) + gathers -------------------------

__device__ __forceinline__ void dense64_bf(const uint4* __restrict__ hp8, const float* __restrict__ W, float acc[64]) {
#pragma unroll 1
    for (int kk = 0; kk < 4; ++kk) {
        float hreg[16];
        uint4 va = hp8[kk * 2], vb = hp8[kk * 2 + 1];
        hreg[0] = unpack_lo(va.x); hreg[1] = unpack_hi(va.x);
        hreg[2] = unpack_lo(va.y); hreg[3] = unpack_hi(va.y);
        hreg[4] = unpack_lo(va.z); hreg[5] = unpack_hi(va.z);
        hreg[6] = unpack_lo(va.w); hreg[7] = unpack_hi(va.w);
        hreg[8] = unpack_lo(vb.x); hreg[9] = unpack_hi(vb.x);
        hreg[10] = unpack_lo(vb.y); hreg[11] = unpack_hi(vb.y);
        hreg[12] = unpack_lo(vb.z); hreg[13] = unpack_hi(vb.z);
        hreg[14] = unpack_lo(vb.w); hreg[15] = unpack_hi(vb.w);
        const float* Wp = W + kk * 16 * 64;
#pragma unroll
        for (int k = 0; k < 16; ++k) {
            float hv = hreg[k];
#pragma unroll
            for (int c = 0; c < 64; ++c)
                acc[c] = fmaf(hv, Wp[k * 64 + c], acc[c]);
        }
    }
}

__device__ __forceinline__ void gather64_f32(const float* __restrict__ ub, int beg, int end,
                                             const int* __restrict__ csr_src, const float* __restrict__ csr_w,
                                             float acc[64]) {
    if (beg < 0) beg = 0;
    if (end > E) end = E;
    for (int i = beg; i < end; ++i) {
        unsigned s = clamp_src(csr_src[i]);
        float w = csr_w[i];
        const float4* up = (const float4*)(ub + (size_t)s * 64);
#pragma unroll
        for (int q = 0; q < 16; ++q) {
            float4 v = up[q];
            acc[q * 4 + 0] = fmaf(w, v.x, acc[q * 4 + 0]);
            acc[q * 4 + 1] = fmaf(w, v.y, acc[q * 4 + 1]);
            acc[q * 4 + 2] = fmaf(w, v.z, acc[q * 4 + 2]);
            acc[q * 4 + 3] = fmaf(w, v.w, acc[q * 4 + 3]);
        }
    }
}

__device__ __forceinline__ void gather64_bf(const char* __restrict__ ub, int beg, int end,
                                            const int* __restrict__ csr_src, const float* __restrict__ csr_w,
                                            float acc[64]) {
    if (beg < 0) beg = 0;
    if (end > E) end = E;
    for (int i = beg; i < end; ++i) {
        unsigned s = clamp_src(csr_src[i]);
        float w = csr_w[i];
        const uint4* up = (const uint4*)(ub + (size_t)s * 128);
#pragma unroll
        for (int q = 0; q < 8; ++q) {
            uint4 v = up[q];
            acc[q * 8 + 0] = fmaf(w, unpack_lo(v.x), acc[q * 8 + 0]);
            acc[q * 8 + 1] = fmaf(w, unpack_hi(v.x), acc[q * 8 + 1]);
            acc[q * 8 + 2] = fmaf(w, unpack_lo(v.y), acc[q * 8 + 2]);
            acc[q * 8 + 3] = fmaf(w, unpack_hi(v.y), acc[q * 8 + 3]);
            acc[q * 8 + 4] = fmaf(w, unpack_lo(v.z), acc[q * 8 + 4]);
            acc[q * 8 + 5] = fmaf(w, unpack_hi(v.z), acc[q * 8 + 5]);
            acc[q * 8 + 6] = fmaf(w, unpack_lo(v.w), acc[q * 8 + 6]);
            acc[q * 8 + 7] = fmaf(w, unpack_hi(v.w), acc[q * 8 + 7]);
        }
    }
}

// ------------------------- Horner hop kernels (64-thread blocks) -------------------------
// u_out = [A u_in] + h1[gb] @ W. u_in==null -> pure matmul (Horner start).
// OUTBF: write bf16 into full-batch buffer at batch gb; else fp32 chunk-local.

template<bool OUTBF>
__global__ __launch_bounds__(64) void hop_kernel(const float* __restrict__ u_in, const int* __restrict__ rowptr,
                                                 const int* __restrict__ csr_src, const float* __restrict__ csr_w,
                                                 const uint4* __restrict__ h1, int b0, int bshift, int bmask,
                                                 const float* __restrict__ W, void* __restrict__ out) {
    int bl = blockIdx.x & bmask;
    int n = (blockIdx.x >> bshift) * blockDim.x + threadIdx.x;
    if (n >= N) return;
    int gb = b0 + bl;
    float acc[64];
#pragma unroll
    for (int f = 0; f < 64; ++f) acc[f] = 0.f;
    if (u_in)
        gather64_f32(u_in + (size_t)bl * N * 64, rowptr[n], rowptr[n + 1], csr_src, csr_w, acc);
    dense64_bf(h1 + ((size_t)gb * N + n) * 8, W, acc);
    if constexpr (OUTBF)
        store_row64_bf((char*)out + ((size_t)gb * N + n) * 128, acc);
    else
        store_row64_f32((float*)out + ((size_t)bl * N + n) * 64, acc);
}

// ------------------------- fused final hop: gather + dense + bias + BN + leaky + project ----

template<bool UBF>
__global__ __launch_bounds__(256) void hop64_final_kernel(const void* __restrict__ u_in, const int* __restrict__ rowptr,
                                                          const int* __restrict__ csr_src, const float* __restrict__ csr_w,
                                                          const uint4* __restrict__ h1, const float* __restrict__ W,
                                                          const float* __restrict__ bias,
                                                          const float* __restrict__ gamma, const float* __restrict__ beta,
                                                          const float* __restrict__ W2, float* __restrict__ y) {
    int gid = blockIdx.x * blockDim.x + threadIdx.x;
    int wave = gid >> 6, lane = gid & 63;
    int n = wave * 8 + (lane >> 3);
    int b = lane & 7;
    if (n >= N) return;
    float acc[64];
#pragma unroll
    for (int f = 0; f < 64; ++f) acc[f] = bias[f];
    int beg = rowptr[n], end = rowptr[n + 1];
    if constexpr (UBF)
        gather64_bf((const char*)u_in + (size_t)b * N * 128, beg, end, csr_src, csr_w, acc);
    else
        gather64_f32((const float*)u_in + (size_t)b * N * 64, beg, end, csr_src, csr_w, acc);
    dense64_bf(h1 + ((size_t)b * N + n) * 8, W, acc);
    const float* gp = gamma + (size_t)n * 64;
    const float* bp = beta + (size_t)n * 64;
#pragma unroll
    for (int f = 0; f < 64; ++f) {
        float v = acc[f];
        float s = v, s2 = v * v;
        s += __shfl_xor(s, 1);  s += __shfl_xor(s, 2);  s += __shfl_xor(s, 4);
        s2 += __shfl_xor(s2, 1); s2 += __shfl_xor(s2, 2); s2 += __shfl_xor(s2, 4);
        float mean = s * 0.125f;
        float var = fmaf(-mean, mean, s2 * 0.125f);
        float xn = (v - mean) * rsqrtf(var + BN_EPS);
        float o = fmaf(gp[f], xn, bp[f]);
        acc[f] = (o >= 0.f) ? o : NEG * o;
    }
    size_t bn3 = ((size_t)b * N + n) * 3;
#pragma unroll
    for (int k = 0; k < 4; ++k) {
#pragma unroll
        for (int c = 0; c < 3; ++c) {
            float s = 0.f;
#pragma unroll
            for (int f = 0; f < 64; ++f)
                s = fmaf(acc[f], W2[k * 192 + f * 3 + c], s);
            y[(size_t)k * B * N * 3 + bn3 + c] = s;
        }
    }
}

// ------------------------- 3-dim propagation (layer 2 Horner) -------------------------

__global__ __launch_bounds__(256) void qprop_kernel(const float* __restrict__ vin, const int* __restrict__ rowptr,
                                                    const int* __restrict__ csr_src, const float* __restrict__ csr_w,
                                                    const float* __restrict__ add, float* __restrict__ vout) {
    int b = blockIdx.x & 7;
    int nb = blockIdx.x >> 3;
    int n = nb * blockDim.x + threadIdx.x;
    if (n >= N) return;
    float a0 = 0.f, a1 = 0.f, a2 = 0.f;
    int beg = rowptr[n], end = rowptr[n + 1];
    if (beg < 0) beg = 0;
    if (end > E) end = E;
    const float* base = vin + (size_t)b * N * 3;
    for (int i = beg; i < end; ++i) {
        unsigned s = clamp_src(csr_src[i]);
        float w = csr_w[i];
        const float* p = base + (size_t)s * 3;
        a0 = fmaf(w, p[0], a0);
        a1 = fmaf(w, p[1], a1);
        a2 = fmaf(w, p[2], a2);
    }
    const float* ap = add + ((size_t)b * N + n) * 3;
    float* op = vout + ((size_t)b * N + n) * 3;
    op[0] = a0 + ap[0];
    op[1] = a1 + ap[1];
    op[2] = a2 + ap[2];
}

__global__ __launch_bounds__(256) void qfinal_kernel(const float* __restrict__ vin, const int* __restrict__ rowptr,
                                                     const int* __restrict__ csr_src, const float* __restrict__ csr_w,
                                                     const float* __restrict__ y0, const float* __restrict__ b2,
                                                     const float* __restrict__ vmin, const float* __restrict__ vmax,
                                                     float* __restrict__ out) {
    int b = blockIdx.x & 7;
    int nb = blockIdx.x >> 3;
    int n = nb * blockDim.x + threadIdx.x;
    if (n >= N) return;
    float a0 = 0.f, a1 = 0.f, a2 = 0.f;
    int beg = rowptr[n], end = rowptr[n + 1];
    if (beg < 0) beg = 0;
    if (end > E) end = E;
    const float* base = vin + (size_t)b * N * 3;
    for (int i = beg; i < end; ++i) {
        unsigned s = clamp_src(csr_src[i]);
        float w = csr_w[i];
        const float* p = base + (size_t)s * 3;
        a0 = fmaf(w, p[0], a0);
        a1 = fmaf(w, p[1], a1);
        a2 = fmaf(w, p[2], a2);
    }
    size_t bn3 = ((size_t)b * N + n) * 3;
    const float* yp = y0 + bn3;
    float g0 = a0 + yp[0] + b2[0];
    float g1 = a1 + yp[1] + b2[1];
    float g2 = a2 + yp[2] + b2[2];
    float mn0 = vmin[n * 3 + 0], mx0 = vmax[n * 3 + 0];
    float mn1 = vmin[n * 3 + 1], mx1 = vmax[n * 3 + 1];
    float mn2 = vmin[n * 3 + 2], mx2 = vmax[n * 3 + 2];
    float* op = out + bn3;
    op[0] = mn0 + (mx0 - mn0) / (1.f + expf(g0));
    op[1] = mn1 + (mx1 - mn1) / (1.f + expf(g1));
    op[2] = mn2 + (mx2 - mn2) / (1.f + expf(g2));
}

// ------------------------- host launcher -------------------------

extern "C" void kernel_launch(void* const* d_in, const int* in_sizes, int n_in,
                              void* d_out, int out_size, void* d_ws, size_t ws_size,
                              hipStream_t stream) {
    const float* x      = (const float*)d_in[0];
    const int*   ei     = (const int*)d_in[1];
    const int*   rowi   = ei;
    const int*   coli   = ei + E;
    const float* vmin   = (const float*)d_in[2];
    const float* vmax   = (const float*)d_in[3];
    const float* W0     = (const float*)d_in[4];
    const float* b0v    = (const float*)d_in[5];
    const float* W1     = (const float*)d_in[6];
    const float* b1v    = (const float*)d_in[7];
    const float* W2     = (const float*)d_in[8];
    const float* b2v    = (const float*)d_in[9];
    const float* gamma0 = (const float*)d_in[10];
    const float* beta0  = (const float*)d_in[11];
    const float* gamma1 = (const float*)d_in[12];
    const float* beta1  = (const float*)d_in[13];
    float* out = (float*)d_out;

    const size_t PC   = (size_t)N * 64;            // 3.2M fl: one batch of 64-dim fp32 state
    const size_t BN3  = (size_t)B * N * 3;         // 1.2M fl
    const size_t H1FL = (size_t)B * N * 32;        // 12.8M fl: full-batch 64-dim bf16
    const size_t XBFL = (size_t)B * N * 2;         // 0.8M fl: one 4-dim bf16 buffer
    const size_t avail_fl = ws_size / 4;

    // csr block size in floats
    auto rnd = [](size_t nf) { return (nf + 63) & ~(size_t)63; };
    const size_t csr_fl = rnd(N) + rnd(E) + rnd(N + 1) + rnd(N) + 256 + 256 + rnd(N) + rnd(E);

    // mode: cc = batch chunk width for fp32 Horner state; cc=8 -> no u2full needed
    int cc;
    size_t yv_fl = rnd(4 * BN3) + 2 * rnd(BN3);    // 7.2M fl
    auto shared_need = [&](int c) { return (size_t)2 * c * PC > yv_fl ? (size_t)2 * c * PC : yv_fl; };
    auto tot_chunked = [&](int c) { return csr_fl + H1FL + H1FL + shared_need(c); };
    size_t tot_full = csr_fl + H1FL + 2 * 8 * PC;  // cc=8, no u2full
    if (avail_fl >= tot_full + (1 << 20))      cc = 8;
    else if (avail_fl >= tot_chunked(4) + (1 << 20)) cc = 4;
    else if (avail_fl >= tot_chunked(2) + (1 << 20)) cc = 2;
    else cc = 1;   // 33.8M fl = 135 MB, below the 142 MB known-good floor

    // ---- allocate ----
    size_t off = 0;
    auto alloc = [&](size_t nfloats) -> float* {
        float* p = (float*)d_ws + off;
        off += rnd(nfloats);
        return p;
    };
    float* deg     = alloc(N);
    float* csr_w   = alloc(E);
    int*   rowptr  = (int*)alloc(N + 1);
    int*   part    = (int*)alloc(N);
    int*   bsum    = (int*)alloc(256);
    int*   boff    = (int*)alloc(256);
    int*   cursor  = (int*)alloc(N);
    int*   csr_src = (int*)alloc(E);
    float* h1      = alloc(H1FL);                  // full-batch bf16

    float *u_a, *u_b, *u2full = nullptr, *shared;
    uint2 *xb1, *xb2, *xb3;
    float *y, *v_a, *v_b;
    if (cc == 8) {
        u_a = alloc(8 * PC);
        u_b = alloc(8 * PC);
        // xb / y / v live inside u_b (dead before/after u_b's live range)
        xb1 = (uint2*)u_b; xb2 = (uint2*)(u_b + XBFL); xb3 = (uint2*)(u_b + 2 * XBFL);
        y = u_b; v_a = u_b + rnd(4 * BN3); v_b = v_a + rnd(BN3);
    } else {
        u2full = alloc(H1FL);                      // full-batch bf16 (hop-2 result)
        shared = alloc(shared_need(cc));
        u_a = shared; u_b = shared + (size_t)cc * PC;
        xb1 = (uint2*)shared; xb2 = (uint2*)(shared + XBFL); xb3 = (uint2*)(shared + 2 * XBFL);
        y = shared; v_a = shared + rnd(4 * BN3); v_b = v_a + rnd(BN3);
    }

    const int GE = (E + 255) / 256;
    const int GN = (N + 255) / 256;
    const int GT = (B * N + 255) / 256;
    const int GH = (N + 63) / 64;                  // 782 blocks per batch for hop kernels
    dim3 blk(256);
    int bshift = (cc == 8) ? 3 : (cc == 4) ? 2 : (cc == 2) ? 1 : 0;
    int bmask = cc - 1;

    // CSR build
    hipMemsetAsync(deg, 0, N * sizeof(float), stream);
    hipMemsetAsync(cursor, 0, N * sizeof(int), stream);
    deg_kernel<<<GE, blk, 0, stream>>>(coli, deg);
    scan1_kernel<<<GN, blk, 0, stream>>>(deg, part, bsum);
    scan2_kernel<<<1, blk, 0, stream>>>(bsum, boff, GN, rowptr);
    scan3_kernel<<<GN, blk, 0, stream>>>(part, boff, rowptr);
    fill_kernel<<<GE, blk, 0, stream>>>(rowi, coli, deg, rowptr, cursor, csr_src, csr_w);

    // layer 0: 3 hops at 4-dim (bf16 out), then fused matmul+BN+leaky -> h1 (full batch, bf16)
    xprop_kernel<false><<<GN * 8, blk, 0, stream>>>(x,   rowptr, csr_src, csr_w, xb1);
    xprop_kernel<true><<<GN * 8, blk, 0, stream>>>(xb1, rowptr, csr_src, csr_w, xb2);
    xprop_kernel<true><<<GN * 8, blk, 0, stream>>>(xb2, rowptr, csr_src, csr_w, xb3);
    fused0_kernel<<<GT, blk, 0, stream>>>(x, xb1, xb2, xb3, W0, b0v, gamma0, beta0, h1);

    // layer 1 Horner over W1 (batch-chunked fp32 state), final hop fused full-batch
    if (cc == 8) {
        hop_kernel<false><<<GH * 8, dim3(64), 0, stream>>>(nullptr, rowptr, csr_src, csr_w,
                                                           (const uint4*)h1, 0, 3, 7, W1 + 3 * 4096, u_a);
        hop_kernel<false><<<GH * 8, dim3(64), 0, stream>>>(u_a, rowptr, csr_src, csr_w,
                                                           (const uint4*)h1, 0, 3, 7, W1 + 2 * 4096, u_b);
        hop_kernel<false><<<GH * 8, dim3(64), 0, stream>>>(u_b, rowptr, csr_src, csr_w,
                                                           (const uint4*)h1, 0, 3, 7, W1 + 1 * 4096, u_a);
        hop64_final_kernel<false><<<GT, blk, 0, stream>>>(u_a, rowptr, csr_src, csr_w,
                                                          (const uint4*)h1, W1, b1v, gamma1, beta1, W2, y);
    } else {
        for (int b0 = 0; b0 < B; b0 += cc) {
            hop_kernel<false><<<GH * cc, dim3(64), 0, stream>>>(nullptr, rowptr, csr_src, csr_w,
                                                                (const uint4*)h1, b0, bshift, bmask,
                                                                W1 + 3 * 4096, u_a);
            hop_kernel<false><<<GH * cc, dim3(64), 0, stream>>>(u_a, rowptr, csr_src, csr_w,
                                                                (const uint4*)h1, b0, bshift, bmask,
                                                                W1 + 2 * 4096, u_b);
            hop_kernel<true><<<GH * cc, dim3(64), 0, stream>>>(u_b, rowptr, csr_src, csr_w,
                                                               (const uint4*)h1, b0, bshift, bmask,
                                                               W1 + 1 * 4096, u2full);
        }
        hop64_final_kernel<true><<<GT, blk, 0, stream>>>(u2full, rowptr, csr_src, csr_w,
                                                         (const uint4*)h1, W1, b1v, gamma1, beta1, W2, y);
    }

    // layer 2 Horner at 3-dim
    qprop_kernel<<<GN * 8, blk, 0, stream>>>(y + 3 * BN3, rowptr, csr_src, csr_w, y + 2 * BN3, v_a);
    qprop_kernel<<<GN * 8, blk, 0, stream>>>(v_a, rowptr, csr_src, csr_w, y + 1 * BN3, v_b);
    qfinal_kernel<<<GN * 8, blk, 0, stream>>>(v_b, rowptr, csr_src, csr_w, y, b2v, vmin, vmax, out);
}

// Round 4
// 1090.347 us; speedup vs baseline: 1.5142x; 1.0135x over previous
//
#include <hip/hip_runtime.h>
#include <math.h>

constexpr int B = 8;
constexpr int N = 50000;
constexpr int E = 400000;
constexpr float BN_EPS = 1e-5f;
constexpr float NEG = 0.01f;

// ------------------------- bf16 helpers -------------------------

__device__ __forceinline__ unsigned clamp_src(int s) {
    unsigned u = (unsigned)s;
    return (u < (unsigned)N) ? u : 0u;
}

__device__ __forceinline__ unsigned pack_bf16(float a, float b) {
    unsigned ua = __float_as_uint(a);
    unsigned ub = __float_as_uint(b);
    ua = (ua + 0x7FFFu + ((ua >> 16) & 1u)) >> 16;
    ub = (ub + 0x7FFFu + ((ub >> 16) & 1u)) >> 16;
    return (ub << 16) | (ua & 0xFFFFu);
}
__device__ __forceinline__ float unpack_lo(unsigned u) { return __uint_as_float(u << 16); }
__device__ __forceinline__ float unpack_hi(unsigned u) { return __uint_as_float(u & 0xFFFF0000u); }

__device__ __forceinline__ void store_row64_bf(uint4* p, const float acc[64]) {
#pragma unroll
    for (int q = 0; q < 8; ++q) {
        uint4 v;
        v.x = pack_bf16(acc[q * 8 + 0], acc[q * 8 + 1]);
        v.y = pack_bf16(acc[q * 8 + 2], acc[q * 8 + 3]);
        v.z = pack_bf16(acc[q * 8 + 4], acc[q * 8 + 5]);
        v.w = pack_bf16(acc[q * 8 + 6], acc[q * 8 + 7]);
        p[q] = v;
    }
}

// ------------------------- CSR construction -------------------------

__global__ __launch_bounds__(256) void deg_kernel(const int* __restrict__ col, float* __restrict__ deg) {
    int e = blockIdx.x * blockDim.x + threadIdx.x;
    if (e < E) atomicAdd(&deg[clamp_src(col[e])], 1.0f);
}

__global__ __launch_bounds__(256) void scan1_kernel(const float* __restrict__ deg,
                                                    int* __restrict__ part, int* __restrict__ bsum) {
    __shared__ int sm[4];
    int i = blockIdx.x * blockDim.x + threadIdx.x;
    int v = (i < N) ? (int)deg[i] : 0;
    int lane = threadIdx.x & 63, wv = threadIdx.x >> 6;
    int x = v;
#pragma unroll
    for (int off = 1; off < 64; off <<= 1) {
        int t = __shfl_up(x, off);
        if (lane >= off) x += t;
    }
    if (lane == 63) sm[wv] = x;
    __syncthreads();
    int add = 0;
#pragma unroll
    for (int w = 0; w < 4; ++w) if (w < wv) add += sm[w];
    if (i < N) part[i] = x - v + add;
    if (threadIdx.x == blockDim.x - 1) bsum[blockIdx.x] = x + add;
}

__global__ __launch_bounds__(256) void scan2_kernel(const int* __restrict__ bsum, int* __restrict__ boff,
                                                    int nb, int* __restrict__ rowptr) {
    __shared__ int sm[4];
    int i = threadIdx.x;
    int v = (i < nb) ? bsum[i] : 0;
    int lane = i & 63, wv = i >> 6;
    int x = v;
#pragma unroll
    for (int off = 1; off < 64; off <<= 1) {
        int t = __shfl_up(x, off);
        if (lane >= off) x += t;
    }
    if (lane == 63) sm[wv] = x;
    __syncthreads();
    int add = 0;
#pragma unroll
    for (int w = 0; w < 4; ++w) if (w < wv) add += sm[w];
    if (i < nb) boff[i] = x - v + add;
    if (i == 0) rowptr[N] = E;
}

__global__ __launch_bounds__(256) void scan3_kernel(const int* __restrict__ part, const int* __restrict__ boff,
                                                    int* __restrict__ rowptr) {
    int i = blockIdx.x * blockDim.x + threadIdx.x;
    if (i < N) rowptr[i] = part[i] + boff[blockIdx.x];
}

__global__ __launch_bounds__(256) void fill_kernel(const int* __restrict__ row, const int* __restrict__ col,
                                                   const float* __restrict__ deg, const int* __restrict__ rowptr,
                                                   int* __restrict__ cursor, int* __restrict__ csr_src,
                                                   float* __restrict__ csr_w) {
    int e = blockIdx.x * blockDim.x + threadIdx.x;
    if (e >= E) return;
    unsigned r = clamp_src(row[e]), c = clamp_src(col[e]);
    float dr = deg[r], dc = deg[c];
    float w = (dr > 0.f ? rsqrtf(dr) : 0.f) * (dc > 0.f ? rsqrtf(dc) : 0.f);
    unsigned p = (unsigned)(rowptr[c] + atomicAdd(&cursor[c], 1));
    if (p >= (unsigned)E) p = E - 1;
    csr_src[p] = (int)r;
    csr_w[p] = w;
}

// ------------------------- 4-dim propagation (layer 0), batch-pinned, bf16 out ---------

template<bool INBF>
__global__ __launch_bounds__(256) void xprop_kernel(const void* __restrict__ xin, const int* __restrict__ rowptr,
                                                    const int* __restrict__ csr_src, const float* __restrict__ csr_w,
                                                    uint2* __restrict__ xout) {
    int b = blockIdx.x & 7;
    int n = (blockIdx.x >> 3) * blockDim.x + threadIdx.x;
    if (n >= N) return;
    float a0 = 0.f, a1 = 0.f, a2 = 0.f, a3 = 0.f;
    int beg = rowptr[n], end = rowptr[n + 1];
    if (beg < 0) beg = 0;
    if (end > E) end = E;
    for (int i = beg; i < end; ++i) {
        unsigned s = clamp_src(csr_src[i]);
        float w = csr_w[i];
        if constexpr (!INBF) {
            float4 v = *((const float4*)xin + (size_t)b * N + s);
            a0 = fmaf(w, v.x, a0); a1 = fmaf(w, v.y, a1);
            a2 = fmaf(w, v.z, a2); a3 = fmaf(w, v.w, a3);
        } else {
            uint2 v = *((const uint2*)xin + (size_t)b * N + s);
            a0 = fmaf(w, unpack_lo(v.x), a0); a1 = fmaf(w, unpack_hi(v.x), a1);
            a2 = fmaf(w, unpack_lo(v.y), a2); a3 = fmaf(w, unpack_hi(v.y), a3);
        }
    }
    uint2 o;
    o.x = pack_bf16(a0, a1);
    o.y = pack_bf16(a2, a3);
    xout[(size_t)b * N + n] = o;
}

// ------------------------- load the 16-dim concat row -------------------------

__device__ __forceinline__ void load_xv(const float4* __restrict__ x0, const uint2* __restrict__ x1,
                                        const uint2* __restrict__ x2, const uint2* __restrict__ x3,
                                        size_t ro, float xv[16]) {
    float4 v = x0[ro];
    xv[0] = v.x; xv[1] = v.y; xv[2] = v.z; xv[3] = v.w;
    uint2 u1 = x1[ro], u2 = x2[ro], u3 = x3[ro];
    xv[4] = unpack_lo(u1.x); xv[5] = unpack_hi(u1.x); xv[6] = unpack_lo(u1.y); xv[7] = unpack_hi(u1.y);
    xv[8] = unpack_lo(u2.x); xv[9] = unpack_hi(u2.x); xv[10] = unpack_lo(u2.y); xv[11] = unpack_hi(u2.y);
    xv[12] = unpack_lo(u3.x); xv[13] = unpack_hi(u3.x); xv[14] = unpack_lo(u3.y); xv[15] = unpack_hi(u3.y);
}

// ------------------------- layer-0 BN stats: fold gamma0/beta0 into scale/shift --------
// z0 = [x|x1|x2|x3] @ W0 (bias omitted: BN-invariant). 8 nodes x 8 batches per wave.

__global__ __launch_bounds__(256) void stats_kernel(const float4* __restrict__ x0, const uint2* __restrict__ x1,
                                                    const uint2* __restrict__ x2, const uint2* __restrict__ x3,
                                                    const float* __restrict__ W0,
                                                    const float* __restrict__ gamma, const float* __restrict__ beta,
                                                    unsigned* __restrict__ ss) {
    int gid = blockIdx.x * blockDim.x + threadIdx.x;
    int wave = gid >> 6, lane = gid & 63;
    int n = wave * 8 + (lane >> 3);
    int b = lane & 7;
    if (n >= N) return;
    size_t ro = (size_t)b * N + n;
    float xv[16];
    load_xv(x0, x1, x2, x3, ro, xv);
    float z[64];
#pragma unroll
    for (int f = 0; f < 64; ++f) z[f] = 0.f;
#pragma unroll
    for (int kf = 0; kf < 16; ++kf) {
        float xs = xv[kf];
#pragma unroll
        for (int f = 0; f < 64; ++f)
            z[f] = fmaf(xs, W0[kf * 64 + f], z[f]);
    }
    const float* gp = gamma + (size_t)n * 64;
    const float* bp = beta + (size_t)n * 64;
#pragma unroll
    for (int f = 0; f < 64; ++f) {
        float v = z[f];
        float s = v, s2 = v * v;
        s += __shfl_xor(s, 1);  s += __shfl_xor(s, 2);  s += __shfl_xor(s, 4);
        s2 += __shfl_xor(s2, 1); s2 += __shfl_xor(s2, 2); s2 += __shfl_xor(s2, 4);
        float mean = s * 0.125f;
        float var = fmaf(-mean, mean, s2 * 0.125f);
        float rs = rsqrtf(var + BN_EPS);
        float sc = gp[f] * rs;
        float sh = fmaf(-sc, mean, bp[f]);
        if (b == 0) ss[(size_t)n * 64 + f] = pack_bf16(sc, sh);
    }
}

// ------------------------- bf16 gather (128B rows) -------------------------

__device__ __forceinline__ void gather64_bf(const uint4* __restrict__ ub8, int beg, int end,
                                            const int* __restrict__ csr_src, const float* __restrict__ csr_w,
                                            float acc[64]) {
    if (beg < 0) beg = 0;
    if (end > E) end = E;
    for (int i = beg; i < end; ++i) {
        unsigned s = clamp_src(csr_src[i]);
        float w = csr_w[i];
        const uint4* up = ub8 + (size_t)s * 8;
#pragma unroll
        for (int q = 0; q < 8; ++q) {
            uint4 v = up[q];
            acc[q * 8 + 0] = fmaf(w, unpack_lo(v.x), acc[q * 8 + 0]);
            acc[q * 8 + 1] = fmaf(w, unpack_hi(v.x), acc[q * 8 + 1]);
            acc[q * 8 + 2] = fmaf(w, unpack_lo(v.y), acc[q * 8 + 2]);
            acc[q * 8 + 3] = fmaf(w, unpack_hi(v.y), acc[q * 8 + 3]);
            acc[q * 8 + 4] = fmaf(w, unpack_lo(v.z), acc[q * 8 + 4]);
            acc[q * 8 + 5] = fmaf(w, unpack_hi(v.z), acc[q * 8 + 5]);
            acc[q * 8 + 6] = fmaf(w, unpack_lo(v.w), acc[q * 8 + 6]);
            acc[q * 8 + 7] = fmaf(w, unpack_hi(v.w), acc[q * 8 + 7]);
        }
    }
}

// ------------------------- Horner hop, h recomputed on the fly -------------------------
// MODE 0: u_out = h @ Wk (no gather). MODE 1: u_out = A u_in + h @ Wk.
// MODE 2: u_out = A u_in + h @ Wk + bias.
// h[k] = leaky(scale[n,k] * (xv . W0[:,k]) + shift[n,k]) -- never materialized as a row.
// Batch-pinned: b = blockIdx & 7 -> per-XCD 6.4MB gather slice.

template<int MODE>
__global__ __launch_bounds__(256) void hopR_kernel(const uint4* __restrict__ u_in, const int* __restrict__ rowptr,
                                                   const int* __restrict__ csr_src, const float* __restrict__ csr_w,
                                                   const float4* __restrict__ x0, const uint2* __restrict__ x1,
                                                   const uint2* __restrict__ x2, const uint2* __restrict__ x3,
                                                   const float* __restrict__ W0, const unsigned* __restrict__ ss,
                                                   const float* __restrict__ Wk, const float* __restrict__ bias,
                                                   uint4* __restrict__ u_out) {
    int b = blockIdx.x & 7;
    int n = (blockIdx.x >> 3) * blockDim.x + threadIdx.x;
    if (n >= N) return;
    size_t ro = (size_t)b * N + n;
    float xv[16];
    load_xv(x0, x1, x2, x3, ro, xv);
    float acc[64];
    if constexpr (MODE == 2) {
#pragma unroll
        for (int f = 0; f < 64; ++f) acc[f] = bias[f];
    } else {
#pragma unroll
        for (int f = 0; f < 64; ++f) acc[f] = 0.f;
    }
    if constexpr (MODE > 0)
        gather64_bf(u_in + (size_t)b * N * 8, rowptr[n], rowptr[n + 1], csr_src, csr_w, acc);
    const unsigned* ssp = ss + (size_t)n * 64;
#pragma unroll 1
    for (int kq = 0; kq < 16; ++kq) {
        uint4 sq = *(const uint4*)(ssp + kq * 4);
        unsigned sqa[4] = {sq.x, sq.y, sq.z, sq.w};
#pragma unroll
        for (int j = 0; j < 4; ++j) {
            int k = kq * 4 + j;
            float z = 0.f;
#pragma unroll
            for (int kf = 0; kf < 16; ++kf)
                z = fmaf(xv[kf], W0[kf * 64 + k], z);
            float h = fmaf(z, unpack_lo(sqa[j]), unpack_hi(sqa[j]));
            h = (h >= 0.f) ? h : NEG * h;
            const float* wr = Wk + k * 64;
#pragma unroll
            for (int c = 0; c < 64; ++c)
                acc[c] = fmaf(h, wr[c], acc[c]);
        }
    }
    store_row64_bf(u_out + ro * 8, acc);
}

// ------------------------- BN + leaky + W2-projection from z (bf16) -------------------------

__global__ __launch_bounds__(256) void bn_project_kernel(const uint4* __restrict__ z,
                                                         const float* __restrict__ gamma, const float* __restrict__ beta,
                                                         const float* __restrict__ W2, float* __restrict__ y) {
    int gid = blockIdx.x * blockDim.x + threadIdx.x;
    int wave = gid >> 6, lane = gid & 63;
    int n = wave * 8 + (lane >> 3);
    int b = lane & 7;
    if (n >= N) return;
    float acc[64];
    const uint4* zp = z + ((size_t)b * N + n) * 8;
#pragma unroll
    for (int q = 0; q < 8; ++q) {
        uint4 v = zp[q];
        acc[q * 8 + 0] = unpack_lo(v.x); acc[q * 8 + 1] = unpack_hi(v.x);
        acc[q * 8 + 2] = unpack_lo(v.y); acc[q * 8 + 3] = unpack_hi(v.y);
        acc[q * 8 + 4] = unpack_lo(v.z); acc[q * 8 + 5] = unpack_hi(v.z);
        acc[q * 8 + 6] = unpack_lo(v.w); acc[q * 8 + 7] = unpack_hi(v.w);
    }
    const float* gp = gamma + (size_t)n * 64;
    const float* bp = beta + (size_t)n * 64;
#pragma unroll
    for (int f = 0; f < 64; ++f) {
        float v = acc[f];
        float s = v, s2 = v * v;
        s += __shfl_xor(s, 1);  s += __shfl_xor(s, 2);  s += __shfl_xor(s, 4);
        s2 += __shfl_xor(s2, 1); s2 += __shfl_xor(s2, 2); s2 += __shfl_xor(s2, 4);
        float mean = s * 0.125f;
        float var = fmaf(-mean, mean, s2 * 0.125f);
        float xn = (v - mean) * rsqrtf(var + BN_EPS);
        float o = fmaf(gp[f], xn, bp[f]);
        acc[f] = (o >= 0.f) ? o : NEG * o;
    }
    size_t bn3 = ((size_t)b * N + n) * 3;
#pragma unroll
    for (int k = 0; k < 4; ++k) {
#pragma unroll
        for (int c = 0; c < 3; ++c) {
            float s = 0.f;
#pragma unroll
            for (int f = 0; f < 64; ++f)
                s = fmaf(acc[f], W2[k * 192 + f * 3 + c], s);
            y[(size_t)k * B * N * 3 + bn3 + c] = s;
        }
    }
}

// ------------------------- 3-dim propagation (layer 2 Horner) -------------------------

__global__ __launch_bounds__(256) void qprop_kernel(const float* __restrict__ vin, const int* __restrict__ rowptr,
                                                    const int* __restrict__ csr_src, const float* __restrict__ csr_w,
                                                    const float* __restrict__ add, float* __restrict__ vout) {
    int b = blockIdx.x & 7;
    int n = (blockIdx.x >> 3) * blockDim.x + threadIdx.x;
    if (n >= N) return;
    float a0 = 0.f, a1 = 0.f, a2 = 0.f;
    int beg = rowptr[n], end = rowptr[n + 1];
    if (beg < 0) beg = 0;
    if (end > E) end = E;
    const float* base = vin + (size_t)b * N * 3;
    for (int i = beg; i < end; ++i) {
        unsigned s = clamp_src(csr_src[i]);
        float w = csr_w[i];
        const float* p = base + (size_t)s * 3;
        a0 = fmaf(w, p[0], a0);
        a1 = fmaf(w, p[1], a1);
        a2 = fmaf(w, p[2], a2);
    }
    const float* ap = add + ((size_t)b * N + n) * 3;
    float* op = vout + ((size_t)b * N + n) * 3;
    op[0] = a0 + ap[0];
    op[1] = a1 + ap[1];
    op[2] = a2 + ap[2];
}

__global__ __launch_bounds__(256) void qfinal_kernel(const float* __restrict__ vin, const int* __restrict__ rowptr,
                                                     const int* __restrict__ csr_src, const float* __restrict__ csr_w,
                                                     const float* __restrict__ y0, const float* __restrict__ b2,
                                                     const float* __restrict__ vmin, const float* __restrict__ vmax,
                                                     float* __restrict__ out) {
    int b = blockIdx.x & 7;
    int n = (blockIdx.x >> 3) * blockDim.x + threadIdx.x;
    if (n >= N) return;
    float a0 = 0.f, a1 = 0.f, a2 = 0.f;
    int beg = rowptr[n], end = rowptr[n + 1];
    if (beg < 0) beg = 0;
    if (end > E) end = E;
    const float* base = vin + (size_t)b * N * 3;
    for (int i = beg; i < end; ++i) {
        unsigned s = clamp_src(csr_src[i]);
        float w = csr_w[i];
        const float* p = base + (size_t)s * 3;
        a0 = fmaf(w, p[0], a0);
        a1 = fmaf(w, p[1], a1);
        a2 = fmaf(w, p[2], a2);
    }
    size_t bn3 = ((size_t)b * N + n) * 3;
    const float* yp = y0 + bn3;
    float g0 = a0 + yp[0] + b2[0];
    float g1 = a1 + yp[1] + b2[1];
    float g2 = a2 + yp[2] + b2[2];
    float mn0 = vmin[n * 3 + 0], mx0 = vmax[n * 3 + 0];
    float mn1 = vmin[n * 3 + 1], mx1 = vmax[n * 3 + 1];
    float mn2 = vmin[n * 3 + 2], mx2 = vmax[n * 3 + 2];
    float* op = out + bn3;
    op[0] = mn0 + (mx0 - mn0) / (1.f + expf(g0));
    op[1] = mn1 + (mx1 - mn1) / (1.f + expf(g1));
    op[2] = mn2 + (mx2 - mn2) / (1.f + expf(g2));
}

// ------------------------- host launcher -------------------------

extern "C" void kernel_launch(void* const* d_in, const int* in_sizes, int n_in,
                              void* d_out, int out_size, void* d_ws, size_t ws_size,
                              hipStream_t stream) {
    const float* x      = (const float*)d_in[0];
    const int*   ei     = (const int*)d_in[1];
    const int*   rowi   = ei;
    const int*   coli   = ei + E;
    const float* vmin   = (const float*)d_in[2];
    const float* vmax   = (const float*)d_in[3];
    const float* W0     = (const float*)d_in[4];
    const float* W1     = (const float*)d_in[6];
    const float* b1v    = (const float*)d_in[7];
    const float* W2     = (const float*)d_in[8];
    const float* b2v    = (const float*)d_in[9];
    const float* gamma0 = (const float*)d_in[10];
    const float* beta0  = (const float*)d_in[11];
    const float* gamma1 = (const float*)d_in[12];
    const float* beta1  = (const float*)d_in[13];
    float* out = (float*)d_out;

    const size_t BN3  = (size_t)B * N * 3;         // 1.2M fl
    const size_t UFL  = (size_t)B * N * 32;        // 12.8M fl: full-batch 64-dim bf16
    const size_t XBFL = (size_t)B * N * 2;         // 0.8M fl: one 4-dim bf16 buffer

    // ---- allocate (total = 32.1M floats = 128.5 MB, under proven 141 MB floor) ----
    auto rnd = [](size_t nf) { return (nf + 63) & ~(size_t)63; };
    size_t off = 0;
    auto alloc = [&](size_t nfloats) -> float* {
        float* p = (float*)d_ws + off;
        off += rnd(nfloats);
        return p;
    };
    float* deg     = alloc(N);
    float* csr_w   = alloc(E);
    int*   rowptr  = (int*)alloc(N + 1);
    int*   part    = (int*)alloc(N);
    int*   bsum    = (int*)alloc(256);
    int*   boff    = (int*)alloc(256);
    int*   cursor  = (int*)alloc(N);
    int*   csr_src = (int*)alloc(E);
    uint2* xb1     = (uint2*)alloc(XBFL);
    uint2* xb2     = (uint2*)alloc(XBFL);
    uint2* xb3     = (uint2*)alloc(XBFL);
    unsigned* ss   = (unsigned*)alloc((size_t)N * 64);
    float* u_a     = alloc(UFL);
    float* u_b     = alloc(UFL);
    // y, v_a, v_b overlap u_a (dead after the last hop reads it)
    float* y   = u_a;
    float* v_a = u_a + rnd(4 * BN3);
    float* v_b = v_a + rnd(BN3);

    const int GE  = (E + 255) / 256;
    const int GN  = (N + 255) / 256;               // 196
    const int GT  = (B * N + 255) / 256;           // 1563
    const int GB8 = GN * 8;                        // 1568 batch-pinned blocks
    dim3 blk(256);

    // CSR build
    hipMemsetAsync(deg, 0, N * sizeof(float), stream);
    hipMemsetAsync(cursor, 0, N * sizeof(int), stream);
    deg_kernel<<<GE, blk, 0, stream>>>(coli, deg);
    scan1_kernel<<<GN, blk, 0, stream>>>(deg, part, bsum);
    scan2_kernel<<<1, blk, 0, stream>>>(bsum, boff, GN, rowptr);
    scan3_kernel<<<GN, blk, 0, stream>>>(part, boff, rowptr);
    fill_kernel<<<GE, blk, 0, stream>>>(rowi, coli, deg, rowptr, cursor, csr_src, csr_w);

    // layer 0: 3 hops at 4-dim (bf16), then fold BN0 into per-(n,f) scale/shift
    xprop_kernel<false><<<GB8, blk, 0, stream>>>(x,   rowptr, csr_src, csr_w, xb1);
    xprop_kernel<true><<<GB8, blk, 0, stream>>>(xb1, rowptr, csr_src, csr_w, xb2);
    xprop_kernel<true><<<GB8, blk, 0, stream>>>(xb2, rowptr, csr_src, csr_w, xb3);
    stats_kernel<<<GT, blk, 0, stream>>>((const float4*)x, xb1, xb2, xb3, W0, gamma0, beta0, ss);

    // layer 1 Horner over W1, h recomputed per hop, all-bf16 batch-pinned state
    hopR_kernel<0><<<GB8, blk, 0, stream>>>(nullptr, rowptr, csr_src, csr_w,
                                            (const float4*)x, xb1, xb2, xb3, W0, ss,
                                            W1 + 3 * 4096, nullptr, (uint4*)u_a);
    hopR_kernel<1><<<GB8, blk, 0, stream>>>((const uint4*)u_a, rowptr, csr_src, csr_w,
                                            (const float4*)x, xb1, xb2, xb3, W0, ss,
                                            W1 + 2 * 4096, nullptr, (uint4*)u_b);
    hopR_kernel<1><<<GB8, blk, 0, stream>>>((const uint4*)u_b, rowptr, csr_src, csr_w,
                                            (const float4*)x, xb1, xb2, xb3, W0, ss,
                                            W1 + 1 * 4096, nullptr, (uint4*)u_a);
    hopR_kernel<2><<<GB8, blk, 0, stream>>>((const uint4*)u_a, rowptr, csr_src, csr_w,
                                            (const float4*)x, xb1, xb2, xb3, W0, ss,
                                            W1, b1v, (uint4*)u_b);
    bn_project_kernel<<<GT, blk, 0, stream>>>((const uint4*)u_b, gamma1, beta1, W2, y);

    // layer 2 Horner at 3-dim
    qprop_kernel<<<GB8, blk, 0, stream>>>(y + 3 * BN3, rowptr, csr_src, csr_w, y + 2 * BN3, v_a);
    qprop_kernel<<<GB8, blk, 0, stream>>>(v_a, rowptr, csr_src, csr_w, y + 1 * BN3, v_b);
    qfinal_kernel<<<GB8, blk, 0, stream>>>(v_b, rowptr, csr_src, csr_w, y, b2v, vmin, vmax, out);
}

// Round 5
// 1006.310 us; speedup vs baseline: 1.6406x; 1.0835x over previous
//
#include <hip/hip_runtime.h>
#include <math.h>

constexpr int B = 8;
constexpr int N = 50000;
constexpr int E = 400000;
constexpr float BN_EPS = 1e-5f;
constexpr float NEG = 0.01f;

// ------------------------- bf16 helpers -------------------------

__device__ __forceinline__ unsigned clamp_src(int s) {
    unsigned u = (unsigned)s;
    return (u < (unsigned)N) ? u : 0u;
}

__device__ __forceinline__ unsigned pack_bf16(float a, float b) {
    unsigned ua = __float_as_uint(a);
    unsigned ub = __float_as_uint(b);
    ua = (ua + 0x7FFFu + ((ua >> 16) & 1u)) >> 16;
    ub = (ub + 0x7FFFu + ((ub >> 16) & 1u)) >> 16;
    return (ub << 16) | (ua & 0xFFFFu);
}
__device__ __forceinline__ float unpack_lo(unsigned u) { return __uint_as_float(u << 16); }
__device__ __forceinline__ float unpack_hi(unsigned u) { return __uint_as_float(u & 0xFFFF0000u); }

__device__ __forceinline__ void store_row64_bf(uint4* p, const float acc[64]) {
#pragma unroll
    for (int q = 0; q < 8; ++q) {
        uint4 v;
        v.x = pack_bf16(acc[q * 8 + 0], acc[q * 8 + 1]);
        v.y = pack_bf16(acc[q * 8 + 2], acc[q * 8 + 3]);
        v.z = pack_bf16(acc[q * 8 + 4], acc[q * 8 + 5]);
        v.w = pack_bf16(acc[q * 8 + 6], acc[q * 8 + 7]);
        p[q] = v;
    }
}

// ------------------------- CSR construction -------------------------

__global__ __launch_bounds__(256) void deg_kernel(const int* __restrict__ col, float* __restrict__ deg) {
    int e = blockIdx.x * blockDim.x + threadIdx.x;
    if (e < E) atomicAdd(&deg[clamp_src(col[e])], 1.0f);
}

__global__ __launch_bounds__(256) void scan1_kernel(const float* __restrict__ deg,
                                                    int* __restrict__ part, int* __restrict__ bsum) {
    __shared__ int sm[4];
    int i = blockIdx.x * blockDim.x + threadIdx.x;
    int v = (i < N) ? (int)deg[i] : 0;
    int lane = threadIdx.x & 63, wv = threadIdx.x >> 6;
    int x = v;
#pragma unroll
    for (int off = 1; off < 64; off <<= 1) {
        int t = __shfl_up(x, off);
        if (lane >= off) x += t;
    }
    if (lane == 63) sm[wv] = x;
    __syncthreads();
    int add = 0;
#pragma unroll
    for (int w = 0; w < 4; ++w) if (w < wv) add += sm[w];
    if (i < N) part[i] = x - v + add;
    if (threadIdx.x == blockDim.x - 1) bsum[blockIdx.x] = x + add;
}

__global__ __launch_bounds__(256) void scan2_kernel(const int* __restrict__ bsum, int* __restrict__ boff,
                                                    int nb, int* __restrict__ rowptr) {
    __shared__ int sm[4];
    int i = threadIdx.x;
    int v = (i < nb) ? bsum[i] : 0;
    int lane = i & 63, wv = i >> 6;
    int x = v;
#pragma unroll
    for (int off = 1; off < 64; off <<= 1) {
        int t = __shfl_up(x, off);
        if (lane >= off) x += t;
    }
    if (lane == 63) sm[wv] = x;
    __syncthreads();
    int add = 0;
#pragma unroll
    for (int w = 0; w < 4; ++w) if (w < wv) add += sm[w];
    if (i < nb) boff[i] = x - v + add;
    if (i == 0) rowptr[N] = E;
}

__global__ __launch_bounds__(256) void scan3_kernel(const int* __restrict__ part, const int* __restrict__ boff,
                                                    int* __restrict__ rowptr) {
    int i = blockIdx.x * blockDim.x + threadIdx.x;
    if (i < N) rowptr[i] = part[i] + boff[blockIdx.x];
}

__global__ __launch_bounds__(256) void fill_kernel(const int* __restrict__ row, const int* __restrict__ col,
                                                   const float* __restrict__ deg, const int* __restrict__ rowptr,
                                                   int* __restrict__ cursor, int* __restrict__ csr_src,
                                                   float* __restrict__ csr_w) {
    int e = blockIdx.x * blockDim.x + threadIdx.x;
    if (e >= E) return;
    unsigned r = clamp_src(row[e]), c = clamp_src(col[e]);
    float dr = deg[r], dc = deg[c];
    float w = (dr > 0.f ? rsqrtf(dr) : 0.f) * (dc > 0.f ? rsqrtf(dc) : 0.f);
    unsigned p = (unsigned)(rowptr[c] + atomicAdd(&cursor[c], 1));
    if (p >= (unsigned)E) p = E - 1;
    csr_src[p] = (int)r;
    csr_w[p] = w;
}

// ------------------------- 4-dim propagation (layer 0), batch-pinned, bf16 out ---------

template<bool INBF>
__global__ __launch_bounds__(256) void xprop_kernel(const void* __restrict__ xin, const int* __restrict__ rowptr,
                                                    const int* __restrict__ csr_src, const float* __restrict__ csr_w,
                                                    uint2* __restrict__ xout) {
    int b = blockIdx.x & 7;
    int n = (blockIdx.x >> 3) * blockDim.x + threadIdx.x;
    if (n >= N) return;
    float a0 = 0.f, a1 = 0.f, a2 = 0.f, a3 = 0.f;
    int beg = rowptr[n], end = rowptr[n + 1];
    if (beg < 0) beg = 0;
    if (end > E) end = E;
    for (int i = beg; i < end; ++i) {
        unsigned s = clamp_src(csr_src[i]);
        float w = csr_w[i];
        if constexpr (!INBF) {
            float4 v = *((const float4*)xin + (size_t)b * N + s);
            a0 = fmaf(w, v.x, a0); a1 = fmaf(w, v.y, a1);
            a2 = fmaf(w, v.z, a2); a3 = fmaf(w, v.w, a3);
        } else {
            uint2 v = *((const uint2*)xin + (size_t)b * N + s);
            a0 = fmaf(w, unpack_lo(v.x), a0); a1 = fmaf(w, unpack_hi(v.x), a1);
            a2 = fmaf(w, unpack_lo(v.y), a2); a3 = fmaf(w, unpack_hi(v.y), a3);
        }
    }
    uint2 o;
    o.x = pack_bf16(a0, a1);
    o.y = pack_bf16(a2, a3);
    xout[(size_t)b * N + n] = o;
}

// ------------------------- 16-dim concat row loader -------------------------

__device__ __forceinline__ void load_xv(const float4* __restrict__ x0, const uint2* __restrict__ x1,
                                        const uint2* __restrict__ x2, const uint2* __restrict__ x3,
                                        size_t ro, float xv[16]) {
    float4 v = x0[ro];
    xv[0] = v.x; xv[1] = v.y; xv[2] = v.z; xv[3] = v.w;
    uint2 u1 = x1[ro], u2 = x2[ro], u3 = x3[ro];
    xv[4] = unpack_lo(u1.x); xv[5] = unpack_hi(u1.x); xv[6] = unpack_lo(u1.y); xv[7] = unpack_hi(u1.y);
    xv[8] = unpack_lo(u2.x); xv[9] = unpack_hi(u2.x); xv[10] = unpack_lo(u2.y); xv[11] = unpack_hi(u2.y);
    xv[12] = unpack_lo(u3.x); xv[13] = unpack_hi(u3.x); xv[14] = unpack_lo(u3.y); xv[15] = unpack_hi(u3.y);
}

// ------------------------- build h1 = leaky(BN0([x|x1|x2|x3] @ W0)), bf16 full batch ----
// Wave per node; lane = fg*8 + b. Each thread: 8 features x 1 batch -> z[8] in registers.
// BN over batch = shfl_xor(1,2,4) (b in low 3 lane bits). 48 shuffles/thread (vs 384).

__global__ __launch_bounds__(256) void build_h1_kernel(const float4* __restrict__ x0, const uint2* __restrict__ x1,
                                                       const uint2* __restrict__ x2, const uint2* __restrict__ x3,
                                                       const float* __restrict__ W0,
                                                       const float* __restrict__ gamma, const float* __restrict__ beta,
                                                       uint4* __restrict__ h1) {
    int gid = blockIdx.x * blockDim.x + threadIdx.x;
    int node = gid >> 6;
    int lane = gid & 63;
    int fg = lane >> 3, b = lane & 7;
    if (node >= N) return;
    size_t ro = (size_t)b * N + node;
    float xv[16];
    load_xv(x0, x1, x2, x3, ro, xv);
    float z[8];
#pragma unroll
    for (int j = 0; j < 8; ++j) z[j] = 0.f;
#pragma unroll
    for (int kf = 0; kf < 16; ++kf) {
        const float* wr = W0 + kf * 64 + fg * 8;
        float4 wa = *(const float4*)wr;
        float4 wb = *(const float4*)(wr + 4);
        float xs = xv[kf];
        z[0] = fmaf(xs, wa.x, z[0]); z[1] = fmaf(xs, wa.y, z[1]);
        z[2] = fmaf(xs, wa.z, z[2]); z[3] = fmaf(xs, wa.w, z[3]);
        z[4] = fmaf(xs, wb.x, z[4]); z[5] = fmaf(xs, wb.y, z[5]);
        z[6] = fmaf(xs, wb.z, z[6]); z[7] = fmaf(xs, wb.w, z[7]);
    }
    const float* gp = gamma + (size_t)node * 64 + fg * 8;
    const float* bp = beta + (size_t)node * 64 + fg * 8;
    float h[8];
#pragma unroll
    for (int j = 0; j < 8; ++j) {
        float v = z[j];
        float s = v, s2 = v * v;
        s += __shfl_xor(s, 1);  s += __shfl_xor(s, 2);  s += __shfl_xor(s, 4);
        s2 += __shfl_xor(s2, 1); s2 += __shfl_xor(s2, 2); s2 += __shfl_xor(s2, 4);
        float mean = s * 0.125f;
        float var = fmaf(-mean, mean, s2 * 0.125f);
        float rs = rsqrtf(var + BN_EPS);
        float o = fmaf(gp[j] * rs, v - mean, bp[j]);
        h[j] = (o >= 0.f) ? o : NEG * o;
    }
    uint4 o;
    o.x = pack_bf16(h[0], h[1]);
    o.y = pack_bf16(h[2], h[3]);
    o.z = pack_bf16(h[4], h[5]);
    o.w = pack_bf16(h[6], h[7]);
    h1[ro * 8 + fg] = o;
}

// ------------------------- bf16 gather + dense 64x64 -------------------------

__device__ __forceinline__ void gather64_bf(const uint4* __restrict__ ub8, int beg, int end,
                                            const int* __restrict__ csr_src, const float* __restrict__ csr_w,
                                            float acc[64]) {
    if (beg < 0) beg = 0;
    if (end > E) end = E;
    for (int i = beg; i < end; ++i) {
        unsigned s = clamp_src(csr_src[i]);
        float w = csr_w[i];
        const uint4* up = ub8 + (size_t)s * 8;
#pragma unroll
        for (int q = 0; q < 8; ++q) {
            uint4 v = up[q];
            acc[q * 8 + 0] = fmaf(w, unpack_lo(v.x), acc[q * 8 + 0]);
            acc[q * 8 + 1] = fmaf(w, unpack_hi(v.x), acc[q * 8 + 1]);
            acc[q * 8 + 2] = fmaf(w, unpack_lo(v.y), acc[q * 8 + 2]);
            acc[q * 8 + 3] = fmaf(w, unpack_hi(v.y), acc[q * 8 + 3]);
            acc[q * 8 + 4] = fmaf(w, unpack_lo(v.z), acc[q * 8 + 4]);
            acc[q * 8 + 5] = fmaf(w, unpack_hi(v.z), acc[q * 8 + 5]);
            acc[q * 8 + 6] = fmaf(w, unpack_lo(v.w), acc[q * 8 + 6]);
            acc[q * 8 + 7] = fmaf(w, unpack_hi(v.w), acc[q * 8 + 7]);
        }
    }
}

__device__ __forceinline__ void dense64_bf(const uint4* __restrict__ hp8, const float* __restrict__ W, float acc[64]) {
#pragma unroll 1
    for (int kk = 0; kk < 4; ++kk) {
        float hreg[16];
        uint4 va = hp8[kk * 2], vb = hp8[kk * 2 + 1];
        hreg[0] = unpack_lo(va.x); hreg[1] = unpack_hi(va.x);
        hreg[2] = unpack_lo(va.y); hreg[3] = unpack_hi(va.y);
        hreg[4] = unpack_lo(va.z); hreg[5] = unpack_hi(va.z);
        hreg[6] = unpack_lo(va.w); hreg[7] = unpack_hi(va.w);
        hreg[8] = unpack_lo(vb.x); hreg[9] = unpack_hi(vb.x);
        hreg[10] = unpack_lo(vb.y); hreg[11] = unpack_hi(vb.y);
        hreg[12] = unpack_lo(vb.z); hreg[13] = unpack_hi(vb.z);
        hreg[14] = unpack_lo(vb.w); hreg[15] = unpack_hi(vb.w);
        const float* Wp = W + kk * 16 * 64;
#pragma unroll
        for (int k = 0; k < 16; ++k) {
            float hv = hreg[k];
#pragma unroll
            for (int c = 0; c < 64; ++c)
                acc[c] = fmaf(hv, Wp[k * 64 + c], acc[c]);
        }
    }
}

// ------------------------- Horner hop (half-batch chunks of 4) -------------------------
// MODE 0: u_out = h1@Wk. MODE 1: u_out = A u_in + h1@Wk. MODE 2: + bias.
// bl = blockIdx&3 keeps each XCD on at most one 6.4MB batch slice.

template<int MODE>
__global__ __launch_bounds__(256) void hopM_kernel(const uint4* __restrict__ u_in, const int* __restrict__ rowptr,
                                                   const int* __restrict__ csr_src, const float* __restrict__ csr_w,
                                                   const uint4* __restrict__ h1, int b0,
                                                   const float* __restrict__ Wk, const float* __restrict__ bias,
                                                   uint4* __restrict__ u_out) {
    int bl = blockIdx.x & 3;
    int n = (blockIdx.x >> 2) * blockDim.x + threadIdx.x;
    if (n >= N) return;
    float acc[64];
    if constexpr (MODE == 2) {
#pragma unroll
        for (int f = 0; f < 64; ++f) acc[f] = bias[f];
    } else {
#pragma unroll
        for (int f = 0; f < 64; ++f) acc[f] = 0.f;
    }
    if constexpr (MODE > 0)
        gather64_bf(u_in + (size_t)bl * N * 8, rowptr[n], rowptr[n + 1], csr_src, csr_w, acc);
    dense64_bf(h1 + ((size_t)(b0 + bl) * N + n) * 8, Wk, acc);
    store_row64_bf(u_out + ((size_t)bl * N + n) * 8, acc);
}

// ------------------------- BN1 + leaky + W2 projection -------------------------
// Wave per node; lane = fg*8 + b. BN over b via xor(1,2,4); projection partials
// reduced over fg via xor(8,16,32). 84 shuffles/thread total.

__global__ __launch_bounds__(256) void bn_project_kernel(const uint4* __restrict__ zlo, const uint4* __restrict__ zhi,
                                                         const float* __restrict__ gamma, const float* __restrict__ beta,
                                                         const float* __restrict__ W2, float* __restrict__ y) {
    int gid = blockIdx.x * blockDim.x + threadIdx.x;
    int node = gid >> 6;
    int lane = gid & 63;
    int fg = lane >> 3, b = lane & 7;
    if (node >= N) return;
    const uint4* zp = (b < 4) ? (zlo + ((size_t)b * N + node) * 8)
                              : (zhi + ((size_t)(b - 4) * N + node) * 8);
    uint4 v = zp[fg];
    float h[8] = {unpack_lo(v.x), unpack_hi(v.x), unpack_lo(v.y), unpack_hi(v.y),
                  unpack_lo(v.z), unpack_hi(v.z), unpack_lo(v.w), unpack_hi(v.w)};
    const float* gp = gamma + (size_t)node * 64 + fg * 8;
    const float* bp = beta + (size_t)node * 64 + fg * 8;
#pragma unroll
    for (int j = 0; j < 8; ++j) {
        float val = h[j];
        float s = val, s2 = val * val;
        s += __shfl_xor(s, 1);  s += __shfl_xor(s, 2);  s += __shfl_xor(s, 4);
        s2 += __shfl_xor(s2, 1); s2 += __shfl_xor(s2, 2); s2 += __shfl_xor(s2, 4);
        float mean = s * 0.125f;
        float var = fmaf(-mean, mean, s2 * 0.125f);
        float rs = rsqrtf(var + BN_EPS);
        float o = fmaf(gp[j] * rs, val - mean, bp[j]);
        h[j] = (o >= 0.f) ? o : NEG * o;
    }
    float p[12];
#pragma unroll
    for (int k = 0; k < 4; ++k) {
#pragma unroll
        for (int c = 0; c < 3; ++c) {
            float s = 0.f;
#pragma unroll
            for (int j = 0; j < 8; ++j)
                s = fmaf(h[j], W2[k * 192 + (fg * 8 + j) * 3 + c], s);
            p[k * 3 + c] = s;
        }
    }
#pragma unroll
    for (int t = 8; t < 64; t <<= 1) {
#pragma unroll
        for (int i = 0; i < 12; ++i)
            p[i] += __shfl_xor(p[i], t);
    }
    if (fg == 0) {
        size_t bn3 = ((size_t)b * N + node) * 3;
#pragma unroll
        for (int k = 0; k < 4; ++k)
#pragma unroll
            for (int c = 0; c < 3; ++c)
                y[(size_t)k * B * N * 3 + bn3 + c] = p[k * 3 + c];
    }
}

// ------------------------- 3-dim propagation (layer 2 Horner) -------------------------

__global__ __launch_bounds__(256) void qprop_kernel(const float* __restrict__ vin, const int* __restrict__ rowptr,
                                                    const int* __restrict__ csr_src, const float* __restrict__ csr_w,
                                                    const float* __restrict__ add, float* __restrict__ vout) {
    int b = blockIdx.x & 7;
    int n = (blockIdx.x >> 3) * blockDim.x + threadIdx.x;
    if (n >= N) return;
    float a0 = 0.f, a1 = 0.f, a2 = 0.f;
    int beg = rowptr[n], end = rowptr[n + 1];
    if (beg < 0) beg = 0;
    if (end > E) end = E;
    const float* base = vin + (size_t)b * N * 3;
    for (int i = beg; i < end; ++i) {
        unsigned s = clamp_src(csr_src[i]);
        float w = csr_w[i];
        const float* p = base + (size_t)s * 3;
        a0 = fmaf(w, p[0], a0);
        a1 = fmaf(w, p[1], a1);
        a2 = fmaf(w, p[2], a2);
    }
    const float* ap = add + ((size_t)b * N + n) * 3;
    float* op = vout + ((size_t)b * N + n) * 3;
    op[0] = a0 + ap[0];
    op[1] = a1 + ap[1];
    op[2] = a2 + ap[2];
}

__global__ __launch_bounds__(256) void qfinal_kernel(const float* __restrict__ vin, const int* __restrict__ rowptr,
                                                     const int* __restrict__ csr_src, const float* __restrict__ csr_w,
                                                     const float* __restrict__ y0, const float* __restrict__ b2,
                                                     const float* __restrict__ vmin, const float* __restrict__ vmax,
                                                     float* __restrict__ out) {
    int b = blockIdx.x & 7;
    int n = (blockIdx.x >> 3) * blockDim.x + threadIdx.x;
    if (n >= N) return;
    float a0 = 0.f, a1 = 0.f, a2 = 0.f;
    int beg = rowptr[n], end = rowptr[n + 1];
    if (beg < 0) beg = 0;
    if (end > E) end = E;
    const float* base = vin + (size_t)b * N * 3;
    for (int i = beg; i < end; ++i) {
        unsigned s = clamp_src(csr_src[i]);
        float w = csr_w[i];
        const float* p = base + (size_t)s * 3;
        a0 = fmaf(w, p[0], a0);
        a1 = fmaf(w, p[1], a1);
        a2 = fmaf(w, p[2], a2);
    }
    size_t bn3 = ((size_t)b * N + n) * 3;
    const float* yp = y0 + bn3;
    float g0 = a0 + yp[0] + b2[0];
    float g1 = a1 + yp[1] + b2[1];
    float g2 = a2 + yp[2] + b2[2];
    float mn0 = vmin[n * 3 + 0], mx0 = vmax[n * 3 + 0];
    float mn1 = vmin[n * 3 + 1], mx1 = vmax[n * 3 + 1];
    float mn2 = vmin[n * 3 + 2], mx2 = vmax[n * 3 + 2];
    float* op = out + bn3;
    op[0] = mn0 + (mx0 - mn0) / (1.f + expf(g0));
    op[1] = mn1 + (mx1 - mn1) / (1.f + expf(g1));
    op[2] = mn2 + (mx2 - mn2) / (1.f + expf(g2));
}

// ------------------------- host launcher -------------------------

extern "C" void kernel_launch(void* const* d_in, const int* in_sizes, int n_in,
                              void* d_out, int out_size, void* d_ws, size_t ws_size,
                              hipStream_t stream) {
    const float* x      = (const float*)d_in[0];
    const int*   ei     = (const int*)d_in[1];
    const int*   rowi   = ei;
    const int*   coli   = ei + E;
    const float* vmin   = (const float*)d_in[2];
    const float* vmax   = (const float*)d_in[3];
    const float* W0     = (const float*)d_in[4];
    const float* W1     = (const float*)d_in[6];
    const float* b1v    = (const float*)d_in[7];
    const float* W2     = (const float*)d_in[8];
    const float* b2v    = (const float*)d_in[9];
    const float* gamma0 = (const float*)d_in[10];
    const float* beta0  = (const float*)d_in[11];
    const float* gamma1 = (const float*)d_in[12];
    const float* beta1  = (const float*)d_in[13];
    float* out = (float*)d_out;

    const size_t BN3  = (size_t)B * N * 3;         // 1.2M fl
    const size_t H1FL = (size_t)B * N * 32;        // 12.8M fl: full-batch 64-dim bf16
    const size_t UCFL = (size_t)4 * N * 32;        // 6.4M fl: 4-batch 64-dim bf16 chunk
    const size_t XBFL = (size_t)B * N * 2;         // 0.8M fl: one 4-dim bf16 buffer

    // ---- arena: CSR(1.0M) + h1(12.8M) + A/Bb/C(6.4M each) = 34.0M fl = 136 MB ----
    auto rnd = [](size_t nf) { return (nf + 63) & ~(size_t)63; };
    size_t off = 0;
    auto alloc = [&](size_t nfloats) -> float* {
        float* p = (float*)d_ws + off;
        off += rnd(nfloats);
        return p;
    };
    float* deg     = alloc(N);
    float* csr_w   = alloc(E);
    int*   rowptr  = (int*)alloc(N + 1);
    int*   part    = (int*)alloc(N);
    int*   bsum    = (int*)alloc(256);
    int*   boff    = (int*)alloc(256);
    int*   cursor  = (int*)alloc(N);
    int*   csr_src = (int*)alloc(E);
    float* h1      = alloc(H1FL);
    float* uA      = alloc(UCFL);
    float* uB      = alloc(UCFL);
    float* uC      = alloc(UCFL);
    // xb1..3 live inside uC (dead before uC's first write in chunk0 hop4)
    uint2* xb1 = (uint2*)uC;
    uint2* xb2 = (uint2*)(uC + XBFL);
    uint2* xb3 = (uint2*)(uC + 2 * XBFL);
    // y, v_a, v_b live inside h1 (dead after last hop)
    float* y   = h1;
    float* v_a = h1 + rnd(4 * BN3);
    float* v_b = v_a + rnd(BN3);

    const int GE  = (E + 255) / 256;
    const int GN  = (N + 255) / 256;               // 196
    const int GB8 = GN * 8;                        // batch-pinned full-batch grids
    const int GH4 = GN * 4;                        // half-batch hop grids
    const int GW  = (N * 64) / 256;                // 12500: wave-per-node grids
    dim3 blk(256);

    // CSR build
    hipMemsetAsync(deg, 0, N * sizeof(float), stream);
    hipMemsetAsync(cursor, 0, N * sizeof(int), stream);
    deg_kernel<<<GE, blk, 0, stream>>>(coli, deg);
    scan1_kernel<<<GN, blk, 0, stream>>>(deg, part, bsum);
    scan2_kernel<<<1, blk, 0, stream>>>(bsum, boff, GN, rowptr);
    scan3_kernel<<<GN, blk, 0, stream>>>(part, boff, rowptr);
    fill_kernel<<<GE, blk, 0, stream>>>(rowi, coli, deg, rowptr, cursor, csr_src, csr_w);

    // layer 0: 3 hops at 4-dim (bf16), then build h1 = leaky(BN0(xcat @ W0)) full batch
    xprop_kernel<false><<<GB8, blk, 0, stream>>>(x,   rowptr, csr_src, csr_w, xb1);
    xprop_kernel<true><<<GB8, blk, 0, stream>>>(xb1, rowptr, csr_src, csr_w, xb2);
    xprop_kernel<true><<<GB8, blk, 0, stream>>>(xb2, rowptr, csr_src, csr_w, xb3);
    build_h1_kernel<<<GW, blk, 0, stream>>>((const float4*)x, xb1, xb2, xb3, W0, gamma0, beta0, (uint4*)h1);

    // layer 1 Horner over W1, two 4-batch chunks; final-hop z chunks -> uC (b0-3), uB (b4-7)
    hopM_kernel<0><<<GH4, blk, 0, stream>>>(nullptr, rowptr, csr_src, csr_w,
                                            (const uint4*)h1, 0, W1 + 3 * 4096, nullptr, (uint4*)uA);
    hopM_kernel<1><<<GH4, blk, 0, stream>>>((const uint4*)uA, rowptr, csr_src, csr_w,
                                            (const uint4*)h1, 0, W1 + 2 * 4096, nullptr, (uint4*)uB);
    hopM_kernel<1><<<GH4, blk, 0, stream>>>((const uint4*)uB, rowptr, csr_src, csr_w,
                                            (const uint4*)h1, 0, W1 + 1 * 4096, nullptr, (uint4*)uA);
    hopM_kernel<2><<<GH4, blk, 0, stream>>>((const uint4*)uA, rowptr, csr_src, csr_w,
                                            (const uint4*)h1, 0, W1, b1v, (uint4*)uC);

    hopM_kernel<0><<<GH4, blk, 0, stream>>>(nullptr, rowptr, csr_src, csr_w,
                                            (const uint4*)h1, 4, W1 + 3 * 4096, nullptr, (uint4*)uA);
    hopM_kernel<1><<<GH4, blk, 0, stream>>>((const uint4*)uA, rowptr, csr_src, csr_w,
                                            (const uint4*)h1, 4, W1 + 2 * 4096, nullptr, (uint4*)uB);
    hopM_kernel<1><<<GH4, blk, 0, stream>>>((const uint4*)uB, rowptr, csr_src, csr_w,
                                            (const uint4*)h1, 4, W1 + 1 * 4096, nullptr, (uint4*)uA);
    hopM_kernel<2><<<GH4, blk, 0, stream>>>((const uint4*)uA, rowptr, csr_src, csr_w,
                                            (const uint4*)h1, 4, W1, b1v, (uint4*)uB);

    // BN1 + leaky + W2 projection -> y[4][B*N*3] (in h1 region; h1 dead now)
    bn_project_kernel<<<GW, blk, 0, stream>>>((const uint4*)uC, (const uint4*)uB,
                                              gamma1, beta1, W2, y);

    // layer 2 Horner at 3-dim
    qprop_kernel<<<GB8, blk, 0, stream>>>(y + 3 * BN3, rowptr, csr_src, csr_w, y + 2 * BN3, v_a);
    qprop_kernel<<<GB8, blk, 0, stream>>>(v_a, rowptr, csr_src, csr_w, y + 1 * BN3, v_b);
    qfinal_kernel<<<GB8, blk, 0, stream>>>(v_b, rowptr, csr_src, csr_w, y, b2v, vmin, vmax, out);
}

// Round 6
// 908.610 us; speedup vs baseline: 1.8170x; 1.1075x over previous
//
#include <hip/hip_runtime.h>
#include <math.h>

constexpr int B = 8;
constexpr int N = 50000;
constexpr int E = 400000;
constexpr float BN_EPS = 1e-5f;
constexpr float NEG = 0.01f;

// ------------------------- bf16 helpers -------------------------

__device__ __forceinline__ unsigned clamp_src(int s) {
    unsigned u = (unsigned)s;
    return (u < (unsigned)N) ? u : 0u;
}

__device__ __forceinline__ unsigned pack_bf16(float a, float b) {
    unsigned ua = __float_as_uint(a);
    unsigned ub = __float_as_uint(b);
    ua = (ua + 0x7FFFu + ((ua >> 16) & 1u)) >> 16;
    ub = (ub + 0x7FFFu + ((ub >> 16) & 1u)) >> 16;
    return (ub << 16) | (ua & 0xFFFFu);
}
__device__ __forceinline__ float unpack_lo(unsigned u) { return __uint_as_float(u << 16); }
__device__ __forceinline__ float unpack_hi(unsigned u) { return __uint_as_float(u & 0xFFFF0000u); }

__device__ __forceinline__ void store_row64_bf(uint4* p, const float acc[64]) {
#pragma unroll
    for (int q = 0; q < 8; ++q) {
        uint4 v;
        v.x = pack_bf16(acc[q * 8 + 0], acc[q * 8 + 1]);
        v.y = pack_bf16(acc[q * 8 + 2], acc[q * 8 + 3]);
        v.z = pack_bf16(acc[q * 8 + 4], acc[q * 8 + 5]);
        v.w = pack_bf16(acc[q * 8 + 6], acc[q * 8 + 7]);
        p[q] = v;
    }
}

// ------------------------- CSR construction -------------------------

__global__ __launch_bounds__(256) void deg_kernel(const int* __restrict__ col, float* __restrict__ deg) {
    int e = blockIdx.x * blockDim.x + threadIdx.x;
    if (e < E) atomicAdd(&deg[clamp_src(col[e])], 1.0f);
}

__global__ __launch_bounds__(256) void scan1_kernel(const float* __restrict__ deg,
                                                    int* __restrict__ part, int* __restrict__ bsum) {
    __shared__ int sm[4];
    int i = blockIdx.x * blockDim.x + threadIdx.x;
    int v = (i < N) ? (int)deg[i] : 0;
    int lane = threadIdx.x & 63, wv = threadIdx.x >> 6;
    int x = v;
#pragma unroll
    for (int off = 1; off < 64; off <<= 1) {
        int t = __shfl_up(x, off);
        if (lane >= off) x += t;
    }
    if (lane == 63) sm[wv] = x;
    __syncthreads();
    int add = 0;
#pragma unroll
    for (int w = 0; w < 4; ++w) if (w < wv) add += sm[w];
    if (i < N) part[i] = x - v + add;
    if (threadIdx.x == blockDim.x - 1) bsum[blockIdx.x] = x + add;
}

__global__ __launch_bounds__(256) void scan2_kernel(const int* __restrict__ bsum, int* __restrict__ boff,
                                                    int nb, int* __restrict__ rowptr) {
    __shared__ int sm[4];
    int i = threadIdx.x;
    int v = (i < nb) ? bsum[i] : 0;
    int lane = i & 63, wv = i >> 6;
    int x = v;
#pragma unroll
    for (int off = 1; off < 64; off <<= 1) {
        int t = __shfl_up(x, off);
        if (lane >= off) x += t;
    }
    if (lane == 63) sm[wv] = x;
    __syncthreads();
    int add = 0;
#pragma unroll
    for (int w = 0; w < 4; ++w) if (w < wv) add += sm[w];
    if (i < nb) boff[i] = x - v + add;
    if (i == 0) rowptr[N] = E;
}

__global__ __launch_bounds__(256) void scan3_kernel(const int* __restrict__ part, const int* __restrict__ boff,
                                                    int* __restrict__ rowptr) {
    int i = blockIdx.x * blockDim.x + threadIdx.x;
    if (i < N) rowptr[i] = part[i] + boff[blockIdx.x];
}

__global__ __launch_bounds__(256) void fill_kernel(const int* __restrict__ row, const int* __restrict__ col,
                                                   const float* __restrict__ deg, const int* __restrict__ rowptr,
                                                   int* __restrict__ cursor, int* __restrict__ csr_src,
                                                   float* __restrict__ csr_w) {
    int e = blockIdx.x * blockDim.x + threadIdx.x;
    if (e >= E) return;
    unsigned r = clamp_src(row[e]), c = clamp_src(col[e]);
    float dr = deg[r], dc = deg[c];
    float w = (dr > 0.f ? rsqrtf(dr) : 0.f) * (dc > 0.f ? rsqrtf(dc) : 0.f);
    unsigned p = (unsigned)(rowptr[c] + atomicAdd(&cursor[c], 1));
    if (p >= (unsigned)E) p = E - 1;
    csr_src[p] = (int)r;
    csr_w[p] = w;
}

// ------------------------- 4-dim propagation (layer 0), batch-pinned, bf16 out ---------

template<bool INBF>
__global__ __launch_bounds__(256) void xprop_kernel(const void* __restrict__ xin, const int* __restrict__ rowptr,
                                                    const int* __restrict__ csr_src, const float* __restrict__ csr_w,
                                                    uint2* __restrict__ xout) {
    int b = blockIdx.x & 7;
    int n = (blockIdx.x >> 3) * blockDim.x + threadIdx.x;
    if (n >= N) return;
    float a0 = 0.f, a1 = 0.f, a2 = 0.f, a3 = 0.f;
    int beg = rowptr[n], end = rowptr[n + 1];
    if (beg < 0) beg = 0;
    if (end > E) end = E;
    for (int i = beg; i < end; ++i) {
        unsigned s = clamp_src(csr_src[i]);
        float w = csr_w[i];
        if constexpr (!INBF) {
            float4 v = *((const float4*)xin + (size_t)b * N + s);
            a0 = fmaf(w, v.x, a0); a1 = fmaf(w, v.y, a1);
            a2 = fmaf(w, v.z, a2); a3 = fmaf(w, v.w, a3);
        } else {
            uint2 v = *((const uint2*)xin + (size_t)b * N + s);
            a0 = fmaf(w, unpack_lo(v.x), a0); a1 = fmaf(w, unpack_hi(v.x), a1);
            a2 = fmaf(w, unpack_lo(v.y), a2); a3 = fmaf(w, unpack_hi(v.y), a3);
        }
    }
    uint2 o;
    o.x = pack_bf16(a0, a1);
    o.y = pack_bf16(a2, a3);
    xout[(size_t)b * N + n] = o;
}

// ------------------------- 16-dim concat row loader -------------------------

__device__ __forceinline__ void load_xv(const float4* __restrict__ x0, const uint2* __restrict__ x1,
                                        const uint2* __restrict__ x2, const uint2* __restrict__ x3,
                                        size_t ro, float xv[16]) {
    float4 v = x0[ro];
    xv[0] = v.x; xv[1] = v.y; xv[2] = v.z; xv[3] = v.w;
    uint2 u1 = x1[ro], u2 = x2[ro], u3 = x3[ro];
    xv[4] = unpack_lo(u1.x); xv[5] = unpack_hi(u1.x); xv[6] = unpack_lo(u1.y); xv[7] = unpack_hi(u1.y);
    xv[8] = unpack_lo(u2.x); xv[9] = unpack_hi(u2.x); xv[10] = unpack_lo(u2.y); xv[11] = unpack_hi(u2.y);
    xv[12] = unpack_lo(u3.x); xv[13] = unpack_hi(u3.x); xv[14] = unpack_lo(u3.y); xv[15] = unpack_hi(u3.y);
}

// ------------------------- build h1 = leaky(BN0([x|x1|x2|x3] @ W0)), bf16 full batch ----
// Wave per node; lane = fg*8 + b; BN over batch via shfl_xor(1,2,4).

__global__ __launch_bounds__(256) void build_h1_kernel(const float4* __restrict__ x0, const uint2* __restrict__ x1,
                                                       const uint2* __restrict__ x2, const uint2* __restrict__ x3,
                                                       const float* __restrict__ W0,
                                                       const float* __restrict__ gamma, const float* __restrict__ beta,
                                                       uint4* __restrict__ h1) {
    int gid = blockIdx.x * blockDim.x + threadIdx.x;
    int node = gid >> 6;
    int lane = gid & 63;
    int fg = lane >> 3, b = lane & 7;
    if (node >= N) return;
    size_t ro = (size_t)b * N + node;
    float xv[16];
    load_xv(x0, x1, x2, x3, ro, xv);
    float z[8];
#pragma unroll
    for (int j = 0; j < 8; ++j) z[j] = 0.f;
#pragma unroll
    for (int kf = 0; kf < 16; ++kf) {
        const float* wr = W0 + kf * 64 + fg * 8;
        float4 wa = *(const float4*)wr;
        float4 wb = *(const float4*)(wr + 4);
        float xs = xv[kf];
        z[0] = fmaf(xs, wa.x, z[0]); z[1] = fmaf(xs, wa.y, z[1]);
        z[2] = fmaf(xs, wa.z, z[2]); z[3] = fmaf(xs, wa.w, z[3]);
        z[4] = fmaf(xs, wb.x, z[4]); z[5] = fmaf(xs, wb.y, z[5]);
        z[6] = fmaf(xs, wb.z, z[6]); z[7] = fmaf(xs, wb.w, z[7]);
    }
    const float* gp = gamma + (size_t)node * 64 + fg * 8;
    const float* bp = beta + (size_t)node * 64 + fg * 8;
    float h[8];
#pragma unroll
    for (int j = 0; j < 8; ++j) {
        float v = z[j];
        float s = v, s2 = v * v;
        s += __shfl_xor(s, 1);  s += __shfl_xor(s, 2);  s += __shfl_xor(s, 4);
        s2 += __shfl_xor(s2, 1); s2 += __shfl_xor(s2, 2); s2 += __shfl_xor(s2, 4);
        float mean = s * 0.125f;
        float var = fmaf(-mean, mean, s2 * 0.125f);
        float rs = rsqrtf(var + BN_EPS);
        float o = fmaf(gp[j] * rs, v - mean, bp[j]);
        h[j] = (o >= 0.f) ? o : NEG * o;
    }
    uint4 o;
    o.x = pack_bf16(h[0], h[1]);
    o.y = pack_bf16(h[2], h[3]);
    o.z = pack_bf16(h[4], h[5]);
    o.w = pack_bf16(h[6], h[7]);
    h1[ro * 8 + fg] = o;
}

// ------------------------- bf16 gather + dense 64x64 -------------------------

__device__ __forceinline__ void gather64_bf(const uint4* __restrict__ ub8, int beg, int end,
                                            const int* __restrict__ csr_src, const float* __restrict__ csr_w,
                                            float acc[64]) {
    if (beg < 0) beg = 0;
    if (end > E) end = E;
    for (int i = beg; i < end; ++i) {
        unsigned s = clamp_src(csr_src[i]);
        float w = csr_w[i];
        const uint4* up = ub8 + (size_t)s * 8;
#pragma unroll
        for (int q = 0; q < 8; ++q) {
            uint4 v = up[q];
            acc[q * 8 + 0] = fmaf(w, unpack_lo(v.x), acc[q * 8 + 0]);
            acc[q * 8 + 1] = fmaf(w, unpack_hi(v.x), acc[q * 8 + 1]);
            acc[q * 8 + 2] = fmaf(w, unpack_lo(v.y), acc[q * 8 + 2]);
            acc[q * 8 + 3] = fmaf(w, unpack_hi(v.y), acc[q * 8 + 3]);
            acc[q * 8 + 4] = fmaf(w, unpack_lo(v.z), acc[q * 8 + 4]);
            acc[q * 8 + 5] = fmaf(w, unpack_hi(v.z), acc[q * 8 + 5]);
            acc[q * 8 + 6] = fmaf(w, unpack_lo(v.w), acc[q * 8 + 6]);
            acc[q * 8 + 7] = fmaf(w, unpack_hi(v.w), acc[q * 8 + 7]);
        }
    }
}

__device__ __forceinline__ void dense64_bf(const uint4* __restrict__ hp8, const float* __restrict__ W, float acc[64]) {
#pragma unroll 1
    for (int kk = 0; kk < 4; ++kk) {
        float hreg[16];
        uint4 va = hp8[kk * 2], vb = hp8[kk * 2 + 1];
        hreg[0] = unpack_lo(va.x); hreg[1] = unpack_hi(va.x);
        hreg[2] = unpack_lo(va.y); hreg[3] = unpack_hi(va.y);
        hreg[4] = unpack_lo(va.z); hreg[5] = unpack_hi(va.z);
        hreg[6] = unpack_lo(va.w); hreg[7] = unpack_hi(va.w);
        hreg[8] = unpack_lo(vb.x); hreg[9] = unpack_hi(vb.x);
        hreg[10] = unpack_lo(vb.y); hreg[11] = unpack_hi(vb.y);
        hreg[12] = unpack_lo(vb.z); hreg[13] = unpack_hi(vb.z);
        hreg[14] = unpack_lo(vb.w); hreg[15] = unpack_hi(vb.w);
        const float* Wp = W + kk * 16 * 64;
#pragma unroll
        for (int k = 0; k < 16; ++k) {
            float hv = hreg[k];
#pragma unroll
            for (int c = 0; c < 64; ++c)
                acc[c] = fmaf(hv, Wp[k * 64 + c], acc[c]);
        }
    }
}

// ------------------------- Horner hop -------------------------
// MODE 0: u_out = h1@Wk. MODE 1: u_out = A u_in + h1@Wk. MODE 2: + bias.
// bl = blockIdx & bmask -> batch-pinned XCD locality. Local batch bl reads
// u_in slice bl, global batch (b0+bl) reads h1; writes slice bl of u_out.

template<int MODE>
__global__ __launch_bounds__(256) void hopM_kernel(const uint4* __restrict__ u_in, const int* __restrict__ rowptr,
                                                   const int* __restrict__ csr_src, const float* __restrict__ csr_w,
                                                   const uint4* __restrict__ h1, int b0, int bmask, int bshift,
                                                   const float* __restrict__ Wk, const float* __restrict__ bias,
                                                   uint4* __restrict__ u_out) {
    int bl = blockIdx.x & bmask;
    int n = (blockIdx.x >> bshift) * blockDim.x + threadIdx.x;
    if (n >= N) return;
    float acc[64];
    if constexpr (MODE == 2) {
#pragma unroll
        for (int f = 0; f < 64; ++f) acc[f] = bias[f];
    } else {
#pragma unroll
        for (int f = 0; f < 64; ++f) acc[f] = 0.f;
    }
    if constexpr (MODE > 0)
        gather64_bf(u_in + (size_t)bl * N * 8, rowptr[n], rowptr[n + 1], csr_src, csr_w, acc);
    dense64_bf(h1 + ((size_t)(b0 + bl) * N + n) * 8, Wk, acc);
    store_row64_bf(u_out + ((size_t)bl * N + n) * 8, acc);
}

// ------------------------- BN1 + leaky + W2 projection -------------------------
// Wave per node; lane = fg*8 + b. BN over b via xor(1,2,4); projection partials
// reduced over fg via xor(8,16,32).

__global__ __launch_bounds__(256) void bn_project_kernel(const uint4* __restrict__ zlo, const uint4* __restrict__ zhi,
                                                         const float* __restrict__ gamma, const float* __restrict__ beta,
                                                         const float* __restrict__ W2, float* __restrict__ y) {
    int gid = blockIdx.x * blockDim.x + threadIdx.x;
    int node = gid >> 6;
    int lane = gid & 63;
    int fg = lane >> 3, b = lane & 7;
    if (node >= N) return;
    const uint4* zp = (b < 4) ? (zlo + ((size_t)b * N + node) * 8)
                              : (zhi + ((size_t)(b - 4) * N + node) * 8);
    uint4 v = zp[fg];
    float h[8] = {unpack_lo(v.x), unpack_hi(v.x), unpack_lo(v.y), unpack_hi(v.y),
                  unpack_lo(v.z), unpack_hi(v.z), unpack_lo(v.w), unpack_hi(v.w)};
    const float* gp = gamma + (size_t)node * 64 + fg * 8;
    const float* bp = beta + (size_t)node * 64 + fg * 8;
#pragma unroll
    for (int j = 0; j < 8; ++j) {
        float val = h[j];
        float s = val, s2 = val * val;
        s += __shfl_xor(s, 1);  s += __shfl_xor(s, 2);  s += __shfl_xor(s, 4);
        s2 += __shfl_xor(s2, 1); s2 += __shfl_xor(s2, 2); s2 += __shfl_xor(s2, 4);
        float mean = s * 0.125f;
        float var = fmaf(-mean, mean, s2 * 0.125f);
        float rs = rsqrtf(var + BN_EPS);
        float o = fmaf(gp[j] * rs, val - mean, bp[j]);
        h[j] = (o >= 0.f) ? o : NEG * o;
    }
    float p[12];
#pragma unroll
    for (int k = 0; k < 4; ++k) {
#pragma unroll
        for (int c = 0; c < 3; ++c) {
            float s = 0.f;
#pragma unroll
            for (int j = 0; j < 8; ++j)
                s = fmaf(h[j], W2[k * 192 + (fg * 8 + j) * 3 + c], s);
            p[k * 3 + c] = s;
        }
    }
#pragma unroll
    for (int t = 8; t < 64; t <<= 1) {
#pragma unroll
        for (int i = 0; i < 12; ++i)
            p[i] += __shfl_xor(p[i], t);
    }
    if (fg == 0) {
        size_t bn3 = ((size_t)b * N + node) * 3;
#pragma unroll
        for (int k = 0; k < 4; ++k)
#pragma unroll
            for (int c = 0; c < 3; ++c)
                y[(size_t)k * B * N * 3 + bn3 + c] = p[k * 3 + c];
    }
}

// ------------------------- 3-dim propagation (layer 2 Horner) -------------------------

__global__ __launch_bounds__(256) void qprop_kernel(const float* __restrict__ vin, const int* __restrict__ rowptr,
                                                    const int* __restrict__ csr_src, const float* __restrict__ csr_w,
                                                    const float* __restrict__ add, float* __restrict__ vout) {
    int b = blockIdx.x & 7;
    int n = (blockIdx.x >> 3) * blockDim.x + threadIdx.x;
    if (n >= N) return;
    float a0 = 0.f, a1 = 0.f, a2 = 0.f;
    int beg = rowptr[n], end = rowptr[n + 1];
    if (beg < 0) beg = 0;
    if (end > E) end = E;
    const float* base = vin + (size_t)b * N * 3;
    for (int i = beg; i < end; ++i) {
        unsigned s = clamp_src(csr_src[i]);
        float w = csr_w[i];
        const float* p = base + (size_t)s * 3;
        a0 = fmaf(w, p[0], a0);
        a1 = fmaf(w, p[1], a1);
        a2 = fmaf(w, p[2], a2);
    }
    const float* ap = add + ((size_t)b * N + n) * 3;
    float* op = vout + ((size_t)b * N + n) * 3;
    op[0] = a0 + ap[0];
    op[1] = a1 + ap[1];
    op[2] = a2 + ap[2];
}

__global__ __launch_bounds__(256) void qfinal_kernel(const float* __restrict__ vin, const int* __restrict__ rowptr,
                                                     const int* __restrict__ csr_src, const float* __restrict__ csr_w,
                                                     const float* __restrict__ y0, const float* __restrict__ b2,
                                                     const float* __restrict__ vmin, const float* __restrict__ vmax,
                                                     float* __restrict__ out) {
    int b = blockIdx.x & 7;
    int n = (blockIdx.x >> 3) * blockDim.x + threadIdx.x;
    if (n >= N) return;
    float a0 = 0.f, a1 = 0.f, a2 = 0.f;
    int beg = rowptr[n], end = rowptr[n + 1];
    if (beg < 0) beg = 0;
    if (end > E) end = E;
    const float* base = vin + (size_t)b * N * 3;
    for (int i = beg; i < end; ++i) {
        unsigned s = clamp_src(csr_src[i]);
        float w = csr_w[i];
        const float* p = base + (size_t)s * 3;
        a0 = fmaf(w, p[0], a0);
        a1 = fmaf(w, p[1], a1);
        a2 = fmaf(w, p[2], a2);
    }
    size_t bn3 = ((size_t)b * N + n) * 3;
    const float* yp = y0 + bn3;
    float g0 = a0 + yp[0] + b2[0];
    float g1 = a1 + yp[1] + b2[1];
    float g2 = a2 + yp[2] + b2[2];
    float mn0 = vmin[n * 3 + 0], mx0 = vmax[n * 3 + 0];
    float mn1 = vmin[n * 3 + 1], mx1 = vmax[n * 3 + 1];
    float mn2 = vmin[n * 3 + 2], mx2 = vmax[n * 3 + 2];
    float* op = out + bn3;
    op[0] = mn0 + (mx0 - mn0) / (1.f + expf(g0));
    op[1] = mn1 + (mx1 - mn1) / (1.f + expf(g1));
    op[2] = mn2 + (mx2 - mn2) / (1.f + expf(g2));
}

// ------------------------- host launcher -------------------------

extern "C" void kernel_launch(void* const* d_in, const int* in_sizes, int n_in,
                              void* d_out, int out_size, void* d_ws, size_t ws_size,
                              hipStream_t stream) {
    const float* x      = (const float*)d_in[0];
    const int*   ei     = (const int*)d_in[1];
    const int*   rowi   = ei;
    const int*   coli   = ei + E;
    const float* vmin   = (const float*)d_in[2];
    const float* vmax   = (const float*)d_in[3];
    const float* W0     = (const float*)d_in[4];
    const float* W1     = (const float*)d_in[6];
    const float* b1v    = (const float*)d_in[7];
    const float* W2     = (const float*)d_in[8];
    const float* b2v    = (const float*)d_in[9];
    const float* gamma0 = (const float*)d_in[10];
    const float* beta0  = (const float*)d_in[11];
    const float* gamma1 = (const float*)d_in[12];
    const float* beta1  = (const float*)d_in[13];
    float* out = (float*)d_out;

    const size_t BN3  = (size_t)B * N * 3;         // 1.2M fl
    const size_t H1FL = (size_t)B * N * 32;        // 12.8M fl = 51.2 MB (full-batch bf16)
    const size_t UCFL = (size_t)4 * N * 32;        // 6.4M fl  = 25.6 MB (4-batch bf16)
    const size_t XBFL = (size_t)B * N * 2;         // 0.8M fl: one 4-dim bf16 buffer

    auto rnd = [](size_t nf) { return (nf + 63) & ~(size_t)63; };
    size_t off = 0;
    auto alloc = [&](size_t nfloats) -> float* {
        float* p = (float*)d_ws + off;
        off += rnd(nfloats);
        return p;
    };
    float* deg     = alloc(N);
    float* csr_w   = alloc(E);
    int*   rowptr  = (int*)alloc(N + 1);
    int*   part    = (int*)alloc(N);
    int*   bsum    = (int*)alloc(256);
    int*   boff    = (int*)alloc(256);
    int*   cursor  = (int*)alloc(N);
    int*   csr_src = (int*)alloc(E);
    float* h1      = alloc(H1FL);

    // mode: full-batch ping-pong (needs h1 + 2 full u buffers = 157.6 MB total)
    const size_t avail_fl = ws_size / 4;
    const size_t need_full = off + 2 * H1FL + 4096;        // + slack
    bool full = (avail_fl >= need_full);

    float *uA, *uB, *uC = nullptr;
    if (full) {
        uA = alloc(H1FL);          // full-batch
        uB = alloc(H1FL);          // full-batch
    } else {
        uA = alloc(UCFL);          // chunk lo
        uB = alloc(UCFL);          // chunk hi (contiguous after uA: uB == uA + UCFL)
        uC = alloc(UCFL);          // scratch chunk
    }
    // xb1..3 live in uA region (dead before first hop writes uA)
    uint2* xb1 = (uint2*)uA;
    uint2* xb2 = (uint2*)((float*)uA + XBFL);
    uint2* xb3 = (uint2*)((float*)uA + 2 * XBFL);
    // y, v_a, v_b live inside h1 (h1 dead after last hop)
    float* y   = h1;
    float* v_a = h1 + rnd(4 * BN3);
    float* v_b = v_a + rnd(BN3);

    const int GE  = (E + 255) / 256;
    const int GN  = (N + 255) / 256;               // 196
    const int GB8 = GN * 8;
    const int GH4 = GN * 4;
    const int GW  = (N * 64) / 256;                // 12500 wave-per-node blocks
    dim3 blk(256);

    // CSR build
    hipMemsetAsync(deg, 0, N * sizeof(float), stream);
    hipMemsetAsync(cursor, 0, N * sizeof(int), stream);
    deg_kernel<<<GE, blk, 0, stream>>>(coli, deg);
    scan1_kernel<<<GN, blk, 0, stream>>>(deg, part, bsum);
    scan2_kernel<<<1, blk, 0, stream>>>(bsum, boff, GN, rowptr);
    scan3_kernel<<<GN, blk, 0, stream>>>(part, boff, rowptr);
    fill_kernel<<<GE, blk, 0, stream>>>(rowi, coli, deg, rowptr, cursor, csr_src, csr_w);

    // layer 0: 3 hops at 4-dim (bf16), then h1 = leaky(BN0(xcat @ W0)) full batch
    xprop_kernel<false><<<GB8, blk, 0, stream>>>(x,   rowptr, csr_src, csr_w, xb1);
    xprop_kernel<true><<<GB8, blk, 0, stream>>>(xb1, rowptr, csr_src, csr_w, xb2);
    xprop_kernel<true><<<GB8, blk, 0, stream>>>(xb2, rowptr, csr_src, csr_w, xb3);
    build_h1_kernel<<<GW, blk, 0, stream>>>((const float4*)x, xb1, xb2, xb3, W0, gamma0, beta0, (uint4*)h1);

    const uint4* H1 = (const uint4*)h1;
    if (full) {
        // 4 full-batch hops: uA = h1@W3; uB = A uA + h1@W2; uA = A uB + h1@W1; uB = A uA + h1@W0 + b1
        hopM_kernel<0><<<GB8, blk, 0, stream>>>(nullptr, rowptr, csr_src, csr_w, H1, 0, 7, 3,
                                                W1 + 3 * 4096, nullptr, (uint4*)uA);
        hopM_kernel<1><<<GB8, blk, 0, stream>>>((const uint4*)uA, rowptr, csr_src, csr_w, H1, 0, 7, 3,
                                                W1 + 2 * 4096, nullptr, (uint4*)uB);
        hopM_kernel<1><<<GB8, blk, 0, stream>>>((const uint4*)uB, rowptr, csr_src, csr_w, H1, 0, 7, 3,
                                                W1 + 1 * 4096, nullptr, (uint4*)uA);
        hopM_kernel<2><<<GB8, blk, 0, stream>>>((const uint4*)uA, rowptr, csr_src, csr_w, H1, 0, 7, 3,
                                                W1, b1v, (uint4*)uB);
        bn_project_kernel<<<GW, blk, 0, stream>>>((const uint4*)uB, (const uint4*)(uB + 4 * (size_t)N * 32),
                                                  gamma1, beta1, W2, y);
    } else {
        // S1 full-batch dense (writes uA∪uB: lo batches 0-3 -> uA, hi 4-7 -> uB, contiguous)
        hopM_kernel<0><<<GB8, blk, 0, stream>>>(nullptr, rowptr, csr_src, csr_w, H1, 0, 7, 3,
                                                W1 + 3 * 4096, nullptr, (uint4*)uA);
        // lo chunk: uA -> uC -> uA -> uC(z_lo)
        hopM_kernel<1><<<GH4, blk, 0, stream>>>((const uint4*)uA, rowptr, csr_src, csr_w, H1, 0, 3, 2,
                                                W1 + 2 * 4096, nullptr, (uint4*)uC);
        hopM_kernel<1><<<GH4, blk, 0, stream>>>((const uint4*)uC, rowptr, csr_src, csr_w, H1, 0, 3, 2,
                                                W1 + 1 * 4096, nullptr, (uint4*)uA);
        hopM_kernel<2><<<GH4, blk, 0, stream>>>((const uint4*)uA, rowptr, csr_src, csr_w, H1, 0, 3, 2,
                                                W1, b1v, (uint4*)uC);
        // hi chunk: uB -> uA -> uB -> uA(z_hi)
        hopM_kernel<1><<<GH4, blk, 0, stream>>>((const uint4*)uB, rowptr, csr_src, csr_w, H1, 4, 3, 2,
                                                W1 + 2 * 4096, nullptr, (uint4*)uA);
        hopM_kernel<1><<<GH4, blk, 0, stream>>>((const uint4*)uA, rowptr, csr_src, csr_w, H1, 4, 3, 2,
                                                W1 + 1 * 4096, nullptr, (uint4*)uB);
        hopM_kernel<2><<<GH4, blk, 0, stream>>>((const uint4*)uB, rowptr, csr_src, csr_w, H1, 4, 3, 2,
                                                W1, b1v, (uint4*)uA);
        bn_project_kernel<<<GW, blk, 0, stream>>>((const uint4*)uC, (const uint4*)uA,
                                                  gamma1, beta1, W2, y);
    }

    // layer 2 Horner at 3-dim
    qprop_kernel<<<GB8, blk, 0, stream>>>(y + 3 * BN3, rowptr, csr_src, csr_w, y + 2 * BN3, v_a);
    qprop_kernel<<<GB8, blk, 0, stream>>>(v_a, rowptr, csr_src, csr_w, y + 1 * BN3, v_b);
    qfinal_kernel<<<GB8, blk, 0, stream>>>(v_b, rowptr, csr_src, csr_w, y, b2v, vmin, vmax, out);
}